// Round 3
// baseline (374.753 us; speedup 1.0000x reference)
//
#include <hip/hip_runtime.h>
#include <cstdint>
#include <cstddef>

// Problem constants (match reference)
#define BTOT    4096
#define SRCLEN  128
#define INDIM   16
#define HDIM    64
#define SEQLEN  100
#define MEANS_N (BTOT * SEQLEN * 4)   // 1638400

// ---------- helpers ----------
// v_rcp_f32-based (no fast-math => plain 1.0f/x emits the exact-div sequence)
__device__ __forceinline__ float sigmoidf_(float x) {
    return __builtin_amdgcn_rcpf(1.0f + __expf(-x));
}
__device__ __forceinline__ float tanhf_(float x) {
    float e = __expf(2.0f * x);
    return 1.0f - 2.0f * __builtin_amdgcn_rcpf(e + 1.0f);
}
// gelu via Abramowitz-Stegun 7.1.26 erf (|err| < 1.5e-7) — replaces libm erff
__device__ __forceinline__ float gelu_fast(float x) {
    float z = fabsf(x) * 0.70710678118654752440f;
    float t = __builtin_amdgcn_rcpf(1.0f + 0.3275911f * z);
    float p = t * (0.254829592f +
              t * (-0.284496736f +
              t * (1.421413741f +
              t * (-1.453152027f +
              t * 1.061405429f))));
    float er = 1.0f - p * __expf(-z * z);
    er = copysignf(er, x);
    return 0.5f * x * (1.0f + er);
}

// ---------- bf16 split helpers (bf16x3 emulated-fp32 MFMA) ----------
typedef __attribute__((ext_vector_type(8))) short s8v;   // 8 bf16 (4 VGPRs) — MFMA A/B frag
typedef __attribute__((ext_vector_type(4))) float f4v;   // 4 fp32 — MFMA C/D frag

__device__ __forceinline__ unsigned short f2bf(float x) {  // RTNE float -> bf16 bits
    unsigned u = __float_as_uint(x);
    unsigned r = (u + 0x7FFFu + ((u >> 16) & 1u)) >> 16;
    return (unsigned short)r;
}
__device__ __forceinline__ float bf2f(unsigned short b) {
    return __uint_as_float(((unsigned)b) << 16);
}
__device__ __forceinline__ void split2(float4 a, float4 b, s8v& hi, s8v& lo) {
    float v[8] = {a.x, a.y, a.z, a.w, b.x, b.y, b.z, b.w};
    #pragma unroll
    for (int j = 0; j < 8; ++j) {
        unsigned short h = f2bf(v[j]);
        hi[j] = (short)h;
        lo[j] = (short)f2bf(v[j] - bf2f(h));
    }
}
__device__ __forceinline__ void split8(const float* v, s8v& hi, s8v& lo) {
    #pragma unroll
    for (int j = 0; j < 8; ++j) {
        unsigned short h = f2bf(v[j]);
        hi[j] = (short)h;
        lo[j] = (short)f2bf(v[j] - bf2f(h));
    }
}
__device__ __forceinline__ void load_bfrag(const float* p, s8v& hi, s8v& lo) {
    float4 a = *(const float4*)p;
    float4 b = *(const float4*)(p + 4);
    split2(a, b, hi, lo);
}

// Merge for the 8-batch activation rebalance, via gfx950 v_permlane32_swap:
// result lanes 0-31 = own_lo (this lane), lanes 32-63 = send_hi from lane-32.
// One VALU op replaces ds_bpermute + v_cndmask (+ lgkmcnt wait).
typedef __attribute__((ext_vector_type(2))) unsigned int u2v;
__device__ __forceinline__ float half_merge(float own_lo, float send_hi) {
    u2v r = __builtin_amdgcn_permlane32_swap(__float_as_uint(own_lo),
                                             __float_as_uint(send_hi),
                                             false, false);
    return __uint_as_float(r[0]);
}

#define MFMA16(a, b, c) __builtin_amdgcn_mfma_f32_16x16x32_bf16((a), (b), (c), 0, 0, 0)

// =====================================================================
// Encoder GRU via MFMA (bf16x3). 8 batches/block, 512 blocks, 2 blocks/CU.
// (unchanged from R2 — 112 µs, MfmaUtil 45%)
// =====================================================================
__global__ __launch_bounds__(256, 2) void enc_mfma_kernel(
    const float* __restrict__ x,
    const float* __restrict__ Wih, const float* __restrict__ bih,
    const float* __restrict__ Whh, const float* __restrict__ bhh,
    float* __restrict__ enc_h)
{
    const int tid  = threadIdx.x;
    const int lane = tid & 63;
    const int w    = tid >> 6;     // wave 0..3
    const int col  = lane & 15;
    const int q    = lane >> 4;
    const int u    = w * 16 + col;
    const int b0   = blockIdx.x * 8;
    // post-rebalance batch row for item j: rows {0,1},{4,5},{2,3},{6,7} for q=0..3
    const int rj0  = (q & 1) * 4 + ((q >> 1) << 1);

    __shared__ __align__(16) unsigned short hiL[2][16][72];
    __shared__ __align__(16) unsigned short loL[2][16][72];
    // [tl][batch 0..7 | zero-row 8][dim] — row 8 is all-zero so lanes q>=2
    // can read a valid zero fragment with no divergence.
    __shared__ __align__(16) unsigned short xhi_l[64][9][16];
    __shared__ __align__(16) unsigned short xlo_l[64][9][16];

    // zero BOTH h double-buffers (rows 8-15 stay zero forever -> zero A rows)
    for (int i = tid; i < 2 * 16 * 72; i += 256) {
        ((unsigned short*)hiL)[i] = 0;
        ((unsigned short*)loL)[i] = 0;
    }
    // zero the x pad row 8 (once)
    for (int i = tid; i < 64 * 16; i += 256) {
        xhi_l[i >> 4][8][i & 15] = 0;
        xlo_l[i >> 4][8][i & 15] = 0;
    }

    // stage one 64-step chunk of x, pre-split into bf16 hi/lo
    auto stage_x = [&](int c) {
        #pragma unroll
        for (int k = 0; k < 8; ++k) {
            int f   = tid + k * 256;          // float4 index in this chunk (0..2047)
            int b   = f >> 8;                 // batch 0..7 (256 float4 per batch)
            int rem = f & 255;
            int tl  = rem >> 2;               // local t 0..63
            int d4  = (rem & 3) << 2;         // dim 0,4,8,12
            const float* xp = x + ((size_t)(b0 + b) * SRCLEN + (c * 64 + tl)) * INDIM + d4;
            float4 v = *(const float4*)xp;
            float vv[4] = {v.x, v.y, v.z, v.w};
            unsigned short hh[4], ll[4];
            #pragma unroll
            for (int j = 0; j < 4; ++j) {
                hh[j] = f2bf(vv[j]);
                ll[j] = f2bf(vv[j] - bf2f(hh[j]));
            }
            *(ushort4*)&xhi_l[tl][b][d4] = make_ushort4(hh[0], hh[1], hh[2], hh[3]);
            *(ushort4*)&xlo_l[tl][b][d4] = make_ushort4(ll[0], ll[1], ll[2], ll[3]);
        }
    };

    const s8v z8 = {0, 0, 0, 0, 0, 0, 0, 0};
    const f4v z4 = {0.0f, 0.0f, 0.0f, 0.0f};

    s8v brh[3], brl[3], bzh[3], bzl[3], bnhh[2], bnhl[2], bnxh, bnxl;
    load_bfrag(Whh + (size_t)u * 64 + q * 8,              brh[0], brl[0]);
    load_bfrag(Whh + (size_t)u * 64 + 32 + q * 8,         brh[1], brl[1]);
    load_bfrag(Whh + (size_t)(64 + u) * 64 + q * 8,       bzh[0], bzl[0]);
    load_bfrag(Whh + (size_t)(64 + u) * 64 + 32 + q * 8,  bzh[1], bzl[1]);
    load_bfrag(Whh + (size_t)(128 + u) * 64 + q * 8,      bnhh[0], bnhl[0]);
    load_bfrag(Whh + (size_t)(128 + u) * 64 + 32 + q * 8, bnhh[1], bnhl[1]);
    if (q < 2) {
        load_bfrag(Wih + (size_t)u * 16 + q * 8,         brh[2], brl[2]);
        load_bfrag(Wih + (size_t)(64 + u) * 16 + q * 8,  bzh[2], bzl[2]);
        load_bfrag(Wih + (size_t)(128 + u) * 16 + q * 8, bnxh, bnxl);
    } else {
        brh[2] = z8; brl[2] = z8; bzh[2] = z8; bzl[2] = z8; bnxh = z8; bnxl = z8;
    }

    const float br   = bih[u] + bhh[u];
    const float bz   = bih[u + 64] + bhh[u + 64];
    const float bnx  = bih[u + 128];
    const float bnh  = bhh[u + 128];

    // unconditional x-frag read bases: lanes q>=2 point at the zero row 8
    const int xb   = (q < 2) ? (col & 7) : 8;
    const int xoff = (q & 1) * 8;
    const unsigned short* xh_base = &xhi_l[0][xb][xoff];
    const unsigned short* xl_base = &xlo_l[0][xb][xoff];

    stage_x(0);
    float hold2[2] = {0.0f, 0.0f};
    __syncthreads();

    int cur = 0;
    for (int t = 0; t < SRCLEN; ++t) {
        if (t == 64) {            // all waves done reading chunk 0 (barrier at t=63)
            stage_x(1);
            __syncthreads();
        }
        const int tl = t & 63;

        const s8v xh = *(const s8v*)(xh_base + (size_t)tl * 144);
        const s8v xl = *(const s8v*)(xl_base + (size_t)tl * 144);

        const s8v ah0 = *(const s8v*)&hiL[cur][col][q * 8];
        const s8v al0 = *(const s8v*)&loL[cur][col][q * 8];
        const s8v ah1 = *(const s8v*)&hiL[cur][col][32 + q * 8];
        const s8v al1 = *(const s8v*)&loL[cur][col][32 + q * 8];

        f4v accr, accz, accnh, accnx;
        accr  = MFMA16(ah0, brh[0], z4);
        accz  = MFMA16(ah0, bzh[0], z4);
        accnh = MFMA16(ah0, bnhh[0], z4);
        accr  = MFMA16(ah0, brl[0], accr);
        accz  = MFMA16(ah0, bzl[0], accz);
        accnh = MFMA16(ah0, bnhl[0], accnh);
        accr  = MFMA16(al0, brh[0], accr);
        accz  = MFMA16(al0, bzh[0], accz);
        accnh = MFMA16(al0, bnhh[0], accnh);
        accr  = MFMA16(ah1, brh[1], accr);
        accz  = MFMA16(ah1, bzh[1], accz);
        accnh = MFMA16(ah1, bnhh[1], accnh);
        accr  = MFMA16(ah1, brl[1], accr);
        accz  = MFMA16(ah1, bzl[1], accz);
        accnh = MFMA16(ah1, bnhl[1], accnh);
        accr  = MFMA16(al1, brh[1], accr);
        accz  = MFMA16(al1, bzh[1], accz);
        accnh = MFMA16(al1, bnhh[1], accnh);
        accr  = MFMA16(xh, brh[2], accr);
        accz  = MFMA16(xh, bzh[2], accz);
        accnx = MFMA16(xh, bnxh, z4);
        accr  = MFMA16(xh, brl[2], accr);
        accz  = MFMA16(xh, bzl[2], accz);
        accnx = MFMA16(xh, bnxl, accnx);
        accr  = MFMA16(xl, brh[2], accr);
        accz  = MFMA16(xl, bzh[2], accz);
        accnx = MFMA16(xl, bnxh, accnx);

        // rebalance: 2 items/lane across all 64 lanes (v_permlane32_swap)
        float pr[2], pz[2], pnh[2], pnx[2];
        pr[0]  = half_merge(accr[0],  accr[2]);
        pr[1]  = half_merge(accr[1],  accr[3]);
        pz[0]  = half_merge(accz[0],  accz[2]);
        pz[1]  = half_merge(accz[1],  accz[3]);
        pnh[0] = half_merge(accnh[0], accnh[2]);
        pnh[1] = half_merge(accnh[1], accnh[3]);
        pnx[0] = half_merge(accnx[0], accnx[2]);
        pnx[1] = half_merge(accnx[1], accnx[3]);

        const int nxt = cur ^ 1;
        #pragma unroll
        for (int j = 0; j < 2; ++j) {
            float r  = sigmoidf_(pr[j] + br);
            float zz = sigmoidf_(pz[j] + bz);
            float n  = tanhf_(pnx[j] + bnx + r * (pnh[j] + bnh));
            float h  = (1.0f - zz) * n + zz * hold2[j];
            hold2[j] = h;
            unsigned short hh = f2bf(h);
            hiL[nxt][rj0 + j][u] = hh;
            loL[nxt][rj0 + j][u] = f2bf(h - bf2f(hh));
        }
        __syncthreads();
        cur ^= 1;
    }

    enc_h[(size_t)(b0 + rj0) * HDIM + u]     = hold2[0];
    enc_h[(size_t)(b0 + rj0 + 1) * HDIM + u] = hold2[1];
}

// =====================================================================
// Decoder GRU via MFMA with out-projection folded into the recurrence.
// (unchanged from R2)
// =====================================================================
__global__ __launch_bounds__(256, 2) void dec_mfma_kernel(
    const float* __restrict__ trg,
    const float* __restrict__ Wih, const float* __restrict__ bih,
    const float* __restrict__ Whh, const float* __restrict__ bhh,
    const float* __restrict__ outW, const float* __restrict__ outb,
    const float* __restrict__ embW, const float* __restrict__ embb,
    const float* __restrict__ enc_h,
    float* __restrict__ dec_o)
{
    const int tid  = threadIdx.x;
    const int lane = tid & 63;
    const int w    = tid >> 6;
    const int col  = lane & 15;
    const int q    = lane >> 4;
    const int u    = w * 16 + col;
    const int b0   = blockIdx.x * 8;
    const int rj0  = (q & 1) * 4 + ((q >> 1) << 1);

    __shared__ __align__(16) unsigned short hiL[2][16][72];
    __shared__ __align__(16) unsigned short loL[2][16][72];
    __shared__ float outW_l[16][64];   // staged outW (for Wcomb + o-frags)
    __shared__ float init_l[8][16];    // init_in per batch

    // ---- stage LDS: outW, init_in, zero pad rows, h0-split into buf0 ----
    for (int i = tid; i < 16 * 64; i += 256) outW_l[i >> 6][i & 63] = outW[i];
    if (tid < 128) {
        int b = tid >> 4, jj = tid & 15;
        float s = embb[jj];
        #pragma unroll
        for (int s4 = 0; s4 < 4; ++s4)
            s = fmaf(embW[jj * 4 + s4], trg[(size_t)(b0 + b) * 4 + s4], s);
        init_l[b][jj] = s;
    }
    // zero rows 8..15 of both buffers (never written with 8 batches)
    for (int i = tid; i < 2 * 8 * 72; i += 256) {
        int buf = i / (8 * 72);
        int rr  = (i / 72) & 7;
        int cc  = i % 72;
        hiL[buf][8 + rr][cc] = 0;
        loL[buf][8 + rr][cc] = 0;
    }
    if (tid < 128) {
        int idx = tid * 4;                  // 512 floats of h0 for this WG
        int bb = idx >> 6, uu = idx & 63;
        float4 v = *(const float4*)(enc_h + (size_t)(b0 + bb) * HDIM + uu);
        float vv[4] = {v.x, v.y, v.z, v.w};
        #pragma unroll
        for (int j = 0; j < 4; ++j) {
            unsigned short hh = f2bf(vv[j]);
            hiL[0][bb][uu + j] = hh;
            loL[0][bb][uu + j] = f2bf(vv[j] - bf2f(hh));
        }
    }
    // h_old for this lane's 2 (batch, unit=u) slots
    float hold2[2];
    hold2[0] = enc_h[(size_t)(b0 + rj0) * HDIM + u];
    hold2[1] = enc_h[(size_t)(b0 + rj0 + 1) * HDIM + u];

    __syncthreads();

    const f4v z4 = {0.0f, 0.0f, 0.0f, 0.0f};

    // ---- fp32 weight rows for this lane's k-slice (k = c*32 + q*8 + jj) ----
    float wh_r[16], wh_z[16], wh_n[16];
    #pragma unroll
    for (int c = 0; c < 2; ++c)
        #pragma unroll
        for (int jj = 0; jj < 8; ++jj) {
            int k = c * 32 + q * 8 + jj;
            wh_r[c * 8 + jj] = Whh[(size_t)u * 64 + k];
            wh_z[c * 8 + jj] = Whh[(size_t)(64 + u) * 64 + k];
            wh_n[c * 8 + jj] = Whh[(size_t)(128 + u) * 64 + k];
        }
    float wi_r[16], wi_z[16], wi_n[16];
    #pragma unroll
    for (int j = 0; j < 16; ++j) {
        wi_r[j] = Wih[(size_t)u * 16 + j];
        wi_z[j] = Wih[(size_t)(64 + u) * 16 + j];
        wi_n[j] = Wih[(size_t)(128 + u) * 16 + j];
    }

    // ---- Wcomb = Wih @ outW; merge into r/z; i_n separate ----
    float m_r[16], m_z[16], c_in[16];
    #pragma unroll
    for (int c = 0; c < 2; ++c)
        #pragma unroll
        for (int jj = 0; jj < 8; ++jj) {
            int k = c * 32 + q * 8 + jj;
            float sr = 0.0f, sz = 0.0f, sn = 0.0f;
            #pragma unroll
            for (int j = 0; j < 16; ++j) {
                float ow = outW_l[j][k];
                sr = fmaf(wi_r[j], ow, sr);
                sz = fmaf(wi_z[j], ow, sz);
                sn = fmaf(wi_n[j], ow, sn);
            }
            m_r[c * 8 + jj]  = wh_r[c * 8 + jj] + sr;
            m_z[c * 8 + jj]  = wh_z[c * 8 + jj] + sz;
            c_in[c * 8 + jj] = sn;
        }

    // ---- B-frags (steady state) ----
    s8v mrh[2], mrl[2], mzh[2], mzl[2], cinh[2], cinl[2], hnh[2], hnl[2];
    split8(m_r,      mrh[0],  mrl[0]);  split8(m_r + 8,  mrh[1],  mrl[1]);
    split8(m_z,      mzh[0],  mzl[0]);  split8(m_z + 8,  mzh[1],  mzl[1]);
    split8(c_in,     cinh[0], cinl[0]); split8(c_in + 8, cinh[1], cinl[1]);
    split8(wh_n,     hnh[0],  hnl[0]);  split8(wh_n + 8, hnh[1],  hnl[1]);
    // step-0 Whh-only r/z frags
    s8v r0h[2], r0l[2], z0h[2], z0l[2];
    split8(wh_r, r0h[0], r0l[0]); split8(wh_r + 8, r0h[1], r0l[1]);
    split8(wh_z, z0h[0], z0l[0]); split8(wh_z + 8, z0h[1], z0l[1]);
    // o-projection frags: B[n=col][k] = outW[col][k]
    s8v owh[2], owl[2];
    {
        float ov[16];
        #pragma unroll
        for (int c = 0; c < 2; ++c)
            #pragma unroll
            for (int jj = 0; jj < 8; ++jj)
                ov[c * 8 + jj] = outW_l[col][c * 32 + q * 8 + jj];
        split8(ov, owh[0], owl[0]); split8(ov + 8, owh[1], owl[1]);
    }

    // ---- folded biases ----
    float b_r = bhh[u] + bih[u];
    float b_z = bhh[u + 64] + bih[u + 64];
    float b_in = bih[u + 128];
    const float b_hn = bhh[u + 128];
    #pragma unroll
    for (int j = 0; j < 16; ++j) {
        float obj = outb[j];
        b_r  = fmaf(obj, wi_r[j], b_r);
        b_z  = fmaf(obj, wi_z[j], b_z);
        b_in = fmaf(obj, wi_n[j], b_in);
    }
    const float ob = outb[col];

    // ---- gi0 from init_in (per lane, its 2 post-rebalance rows) ----
    float g_r[2], g_z[2], g_n[2];
    #pragma unroll
    for (int j2 = 0; j2 < 2; ++j2) {
        int row = rj0 + j2;
        float sr = bih[u] + bhh[u];
        float sz = bih[u + 64] + bhh[u + 64];
        float sn = bih[u + 128];
        #pragma unroll
        for (int j = 0; j < 16; ++j) {
            float iv = init_l[row][j];
            sr = fmaf(wi_r[j], iv, sr);
            sz = fmaf(wi_z[j], iv, sz);
            sn = fmaf(wi_n[j], iv, sn);
        }
        g_r[j2] = sr; g_z[j2] = sz; g_n[j2] = sn;
    }

    // ---- step 0: h1 = GRU(h0, init_in) ----
    {
        const s8v ah0 = *(const s8v*)&hiL[0][col][q * 8];
        const s8v al0 = *(const s8v*)&loL[0][col][q * 8];
        const s8v ah1 = *(const s8v*)&hiL[0][col][32 + q * 8];
        const s8v al1 = *(const s8v*)&loL[0][col][32 + q * 8];
        f4v ar, az, ahn;
        ar  = MFMA16(ah0, r0h[0], z4);
        az  = MFMA16(ah0, z0h[0], z4);
        ahn = MFMA16(ah0, hnh[0], z4);
        ar  = MFMA16(ah0, r0l[0], ar);
        az  = MFMA16(ah0, z0l[0], az);
        ahn = MFMA16(ah0, hnl[0], ahn);
        ar  = MFMA16(al0, r0h[0], ar);
        az  = MFMA16(al0, z0h[0], az);
        ahn = MFMA16(al0, hnh[0], ahn);
        ar  = MFMA16(ah1, r0h[1], ar);
        az  = MFMA16(ah1, z0h[1], az);
        ahn = MFMA16(ah1, hnh[1], ahn);
        ar  = MFMA16(ah1, r0l[1], ar);
        az  = MFMA16(ah1, z0l[1], az);
        ahn = MFMA16(ah1, hnl[1], ahn);
        ar  = MFMA16(al1, r0h[1], ar);
        az  = MFMA16(al1, z0h[1], az);
        ahn = MFMA16(al1, hnh[1], ahn);

        float pr[2], pz[2], pnh[2];
        pr[0]  = half_merge(ar[0],  ar[2]);
        pr[1]  = half_merge(ar[1],  ar[3]);
        pz[0]  = half_merge(az[0],  az[2]);
        pz[1]  = half_merge(az[1],  az[3]);
        pnh[0] = half_merge(ahn[0], ahn[2]);
        pnh[1] = half_merge(ahn[1], ahn[3]);

        #pragma unroll
        for (int j = 0; j < 2; ++j) {
            float r  = sigmoidf_(pr[j] + g_r[j]);
            float zz = sigmoidf_(pz[j] + g_z[j]);
            float n  = tanhf_(g_n[j] + r * (pnh[j] + b_hn));
            float h  = (1.0f - zz) * n + zz * hold2[j];
            hold2[j] = h;
            unsigned short hh = f2bf(h);
            hiL[1][rj0 + j][u] = hh;
            loL[1][rj0 + j][u] = f2bf(h - bf2f(hh));
        }
        __syncthreads();
    }

    // ---- steps 1..99 (merged weights); o_{t-1} by wave (t-1)&3 ----
    for (int t = 1; t < SEQLEN; ++t) {
        const int cur = t & 1;
        const s8v ah0 = *(const s8v*)&hiL[cur][col][q * 8];
        const s8v al0 = *(const s8v*)&loL[cur][col][q * 8];
        const s8v ah1 = *(const s8v*)&hiL[cur][col][32 + q * 8];
        const s8v al1 = *(const s8v*)&loL[cur][col][32 + q * 8];

        if (w == ((t - 1) & 3)) {  // o_{t-1} = h_t @ outW^T + outb (round-robin)
            f4v oa;
            oa = MFMA16(ah0, owh[0], z4);
            oa = MFMA16(ah0, owl[0], oa);
            oa = MFMA16(al0, owh[0], oa);
            oa = MFMA16(ah1, owh[1], oa);
            oa = MFMA16(ah1, owl[1], oa);
            oa = MFMA16(al1, owh[1], oa);
            if (q < 2) {
                #pragma unroll
                for (int i = 0; i < 4; ++i)
                    dec_o[(((size_t)(b0 + q * 4 + i) * SEQLEN) + (t - 1)) * INDIM + col] = oa[i] + ob;
            }
        }

        f4v ar, az, ain, ahn;
        ar  = MFMA16(ah0, mrh[0], z4);
        az  = MFMA16(ah0, mzh[0], z4);
        ain = MFMA16(ah0, cinh[0], z4);
        ahn = MFMA16(ah0, hnh[0], z4);
        ar  = MFMA16(ah0, mrl[0], ar);
        az  = MFMA16(ah0, mzl[0], az);
        ain = MFMA16(ah0, cinl[0], ain);
        ahn = MFMA16(ah0, hnl[0], ahn);
        ar  = MFMA16(al0, mrh[0], ar);
        az  = MFMA16(al0, mzh[0], az);
        ain = MFMA16(al0, cinh[0], ain);
        ahn = MFMA16(al0, hnh[0], ahn);
        ar  = MFMA16(ah1, mrh[1], ar);
        az  = MFMA16(ah1, mzh[1], az);
        ain = MFMA16(ah1, cinh[1], ain);
        ahn = MFMA16(ah1, hnh[1], ahn);
        ar  = MFMA16(ah1, mrl[1], ar);
        az  = MFMA16(ah1, mzl[1], az);
        ain = MFMA16(ah1, cinl[1], ain);
        ahn = MFMA16(ah1, hnl[1], ahn);
        ar  = MFMA16(al1, mrh[1], ar);
        az  = MFMA16(al1, mzh[1], az);
        ain = MFMA16(al1, cinh[1], ain);
        ahn = MFMA16(al1, hnh[1], ahn);

        float pr[2], pz[2], pin[2], pnh[2];
        pr[0]  = half_merge(ar[0],  ar[2]);
        pr[1]  = half_merge(ar[1],  ar[3]);
        pz[0]  = half_merge(az[0],  az[2]);
        pz[1]  = half_merge(az[1],  az[3]);
        pin[0] = half_merge(ain[0], ain[2]);
        pin[1] = half_merge(ain[1], ain[3]);
        pnh[0] = half_merge(ahn[0], ahn[2]);
        pnh[1] = half_merge(ahn[1], ahn[3]);

        const int nxt = cur ^ 1;
        #pragma unroll
        for (int j = 0; j < 2; ++j) {
            float r  = sigmoidf_(pr[j] + b_r);
            float zz = sigmoidf_(pz[j] + b_z);
            float n  = tanhf_(pin[j] + b_in + r * (pnh[j] + b_hn));
            float h  = (1.0f - zz) * n + zz * hold2[j];
            hold2[j] = h;
            unsigned short hh = f2bf(h);
            hiL[nxt][rj0 + j][u] = hh;
            loL[nxt][rj0 + j][u] = f2bf(h - bf2f(hh));
        }
        __syncthreads();
    }

    // ---- epilogue: o_99 = h_100 @ outW^T + outb (buf 0) ----
    if (w == 0) {
        const s8v ah0 = *(const s8v*)&hiL[0][col][q * 8];
        const s8v al0 = *(const s8v*)&loL[0][col][q * 8];
        const s8v ah1 = *(const s8v*)&hiL[0][col][32 + q * 8];
        const s8v al1 = *(const s8v*)&loL[0][col][32 + q * 8];
        f4v oa;
        oa = MFMA16(ah0, owh[0], z4);
        oa = MFMA16(ah0, owl[0], oa);
        oa = MFMA16(al0, owh[0], oa);
        oa = MFMA16(ah1, owh[1], oa);
        oa = MFMA16(ah1, owl[1], oa);
        oa = MFMA16(al1, owh[1], oa);
        if (q < 2) {
            #pragma unroll
            for (int i = 0; i < 4; ++i)
                dec_o[(((size_t)(b0 + q * 4 + i) * SEQLEN) + (SEQLEN - 1)) * INDIM + col] = oa[i] + ob;
        }
    }
}

// =====================================================================
// Heads: 409600 independent rows.
// R5: 4 rows per thread (was 1). The 12 broadcast ds_read_b128 per
// hu-iteration now feed 280 FMAs instead of 70 — LDS pipe (shared per
// CU) drops from the bottleneck (~80-100 µs worth of ds_read issue) to
// ~25% of VALU. Math per row is op-for-op identical.
// Grid: 400 blocks, rows base + tid + k*256 (coalesced float4 loads).
// =====================================================================
__global__ __launch_bounds__(256) void heads_kernel(
    const float* __restrict__ dec_o,
    const float* __restrict__ mW1, const float* __restrict__ mb1,
    const float* __restrict__ mW2, const float* __restrict__ mb2,
    const float* __restrict__ cW1, const float* __restrict__ cb1,
    const float* __restrict__ cW2, const float* __restrict__ cb2,
    float* __restrict__ out)
{
    const int tid = threadIdx.x;

    __shared__ __align__(16) float lW1m[64][16];
    __shared__ __align__(16) float lW1c[64][16];
    // [hu][0..3]=mW2 rows, [4..13]=cW2 rows, [14]=mb1, [15]=cb1
    __shared__ __align__(16) float lW2t[64][16];

    for (int i = tid; i < 1024; i += 256) {
        lW1m[i >> 4][i & 15] = mW1[i];
        lW1c[i >> 4][i & 15] = cW1[i];
    }
    if (tid < 64) {
        #pragma unroll
        for (int j = 0; j < 4; ++j)  lW2t[tid][j]     = mW2[j * 64 + tid];
        #pragma unroll
        for (int j = 0; j < 10; ++j) lW2t[tid][4 + j] = cW2[j * 64 + tid];
        lW2t[tid][14] = mb1[tid];
        lW2t[tid][15] = cb1[tid];
    }
    __syncthreads();

    const size_t rbase = (size_t)blockIdx.x * 1024 + tid;  // + k*256, k=0..3

    float o[4][16];
    #pragma unroll
    for (int k = 0; k < 4; ++k) {
        const float4* op = (const float4*)(dec_o + (rbase + (size_t)k * 256) * 16);
        #pragma unroll
        for (int c = 0; c < 4; ++c) {
            float4 v = op[c];
            o[k][4 * c + 0] = v.x; o[k][4 * c + 1] = v.y;
            o[k][4 * c + 2] = v.z; o[k][4 * c + 3] = v.w;
        }
    }

    float m[4][4], cv[4][10];
    {
        float mb2v[4], cb2v[10];
        #pragma unroll
        for (int j = 0; j < 4; ++j)  mb2v[j] = mb2[j];
        #pragma unroll
        for (int j = 0; j < 10; ++j) cb2v[j] = cb2[j];
        #pragma unroll
        for (int k = 0; k < 4; ++k) {
            #pragma unroll
            for (int j = 0; j < 4; ++j)  m[k][j]  = mb2v[j];
            #pragma unroll
            for (int j = 0; j < 10; ++j) cv[k][j] = cb2v[j];
        }
    }

    #pragma unroll 2
    for (int hu = 0; hu < 64; ++hu) {
        const float4 a0 = *(const float4*)&lW1m[hu][0];
        const float4 a1 = *(const float4*)&lW1m[hu][4];
        const float4 a2 = *(const float4*)&lW1m[hu][8];
        const float4 a3 = *(const float4*)&lW1m[hu][12];
        const float4 c0 = *(const float4*)&lW1c[hu][0];
        const float4 c1 = *(const float4*)&lW1c[hu][4];
        const float4 c2 = *(const float4*)&lW1c[hu][8];
        const float4 c3 = *(const float4*)&lW1c[hu][12];
        const float4 t0 = *(const float4*)&lW2t[hu][0];
        const float4 t1 = *(const float4*)&lW2t[hu][4];
        const float4 t2 = *(const float4*)&lW2t[hu][8];
        const float4 t3 = *(const float4*)&lW2t[hu][12];

        #pragma unroll
        for (int k = 0; k < 4; ++k) {
            float hm = t3.z;  // mb1[hu]
            hm = fmaf(a0.x, o[k][0],  hm); hm = fmaf(a0.y, o[k][1],  hm);
            hm = fmaf(a0.z, o[k][2],  hm); hm = fmaf(a0.w, o[k][3],  hm);
            hm = fmaf(a1.x, o[k][4],  hm); hm = fmaf(a1.y, o[k][5],  hm);
            hm = fmaf(a1.z, o[k][6],  hm); hm = fmaf(a1.w, o[k][7],  hm);
            hm = fmaf(a2.x, o[k][8],  hm); hm = fmaf(a2.y, o[k][9],  hm);
            hm = fmaf(a2.z, o[k][10], hm); hm = fmaf(a2.w, o[k][11], hm);
            hm = fmaf(a3.x, o[k][12], hm); hm = fmaf(a3.y, o[k][13], hm);
            hm = fmaf(a3.z, o[k][14], hm); hm = fmaf(a3.w, o[k][15], hm);
            float gm = gelu_fast(hm);
            m[k][0] = fmaf(t0.x, gm, m[k][0]); m[k][1] = fmaf(t0.y, gm, m[k][1]);
            m[k][2] = fmaf(t0.z, gm, m[k][2]); m[k][3] = fmaf(t0.w, gm, m[k][3]);

            float hc = t3.w;  // cb1[hu]
            hc = fmaf(c0.x, o[k][0],  hc); hc = fmaf(c0.y, o[k][1],  hc);
            hc = fmaf(c0.z, o[k][2],  hc); hc = fmaf(c0.w, o[k][3],  hc);
            hc = fmaf(c1.x, o[k][4],  hc); hc = fmaf(c1.y, o[k][5],  hc);
            hc = fmaf(c1.z, o[k][6],  hc); hc = fmaf(c1.w, o[k][7],  hc);
            hc = fmaf(c2.x, o[k][8],  hc); hc = fmaf(c2.y, o[k][9],  hc);
            hc = fmaf(c2.z, o[k][10], hc); hc = fmaf(c2.w, o[k][11], hc);
            hc = fmaf(c3.x, o[k][12], hc); hc = fmaf(c3.y, o[k][13], hc);
            hc = fmaf(c3.z, o[k][14], hc); hc = fmaf(c3.w, o[k][15], hc);
            float gc = gelu_fast(hc);
            cv[k][0] = fmaf(t1.x, gc, cv[k][0]); cv[k][1] = fmaf(t1.y, gc, cv[k][1]);
            cv[k][2] = fmaf(t1.z, gc, cv[k][2]); cv[k][3] = fmaf(t1.w, gc, cv[k][3]);
            cv[k][4] = fmaf(t2.x, gc, cv[k][4]); cv[k][5] = fmaf(t2.y, gc, cv[k][5]);
            cv[k][6] = fmaf(t2.z, gc, cv[k][6]); cv[k][7] = fmaf(t2.w, gc, cv[k][7]);
            cv[k][8] = fmaf(t3.x, gc, cv[k][8]); cv[k][9] = fmaf(t3.y, gc, cv[k][9]);
        }
    }

    float* means = out;
    float* covs  = out + MEANS_N;
    #pragma unroll
    for (int k = 0; k < 4; ++k) {
        const size_t r = rbase + (size_t)k * 256;
        m[k][2] = fminf(fmaxf(m[k][2], -1.0f), 1.0f);
        m[k][3] = fminf(fmaxf(m[k][3], -1.0f), 1.0f);
        #pragma unroll
        for (int j = 0; j < 4; ++j)  means[r * 4 + j] = m[k][j];
        #pragma unroll
        for (int j = 0; j < 10; ++j) covs[r * 10 + j] = cv[k][j];
    }
}

// =====================================================================
extern "C" void kernel_launch(void* const* d_in, const int* in_sizes, int n_in,
                              void* d_out, int out_size, void* d_ws, size_t ws_size,
                              hipStream_t stream)
{
    const float* x    = (const float*)d_in[0];
    const float* trg  = (const float*)d_in[1];
    const float* eWih = (const float*)d_in[2];
    const float* ebih = (const float*)d_in[3];
    const float* eWhh = (const float*)d_in[4];
    const float* ebhh = (const float*)d_in[5];
    const float* dWih = (const float*)d_in[6];
    const float* dbih = (const float*)d_in[7];
    const float* dWhh = (const float*)d_in[8];
    const float* dbhh = (const float*)d_in[9];
    const float* outW = (const float*)d_in[10];
    const float* outb = (const float*)d_in[11];
    const float* embW = (const float*)d_in[12];
    const float* embb = (const float*)d_in[13];
    const float* mW1  = (const float*)d_in[14];
    const float* mb1  = (const float*)d_in[15];
    const float* mW2  = (const float*)d_in[16];
    const float* mb2  = (const float*)d_in[17];
    const float* cW1  = (const float*)d_in[18];
    const float* cb1  = (const float*)d_in[19];
    const float* cW2  = (const float*)d_in[20];
    const float* cb2  = (const float*)d_in[21];

    float* ws    = (float*)d_ws;
    float* enc_h = ws;                          // 4096*64      = 262144 floats
    float* dec_o = ws + (size_t)BTOT * HDIM;    // 4096*100*16  = 6553600 floats
    float* outp  = (float*)d_out;

    enc_mfma_kernel<<<dim3(BTOT / 8), dim3(256), 0, stream>>>(x, eWih, ebih, eWhh, ebhh, enc_h);
    dec_mfma_kernel<<<dim3(BTOT / 8), dim3(256), 0, stream>>>(trg, dWih, dbih, dWhh, dbhh,
                                                              outW, outb, embW, embb, enc_h, dec_o);
    heads_kernel<<<dim3((BTOT * SEQLEN) / 1024), dim3(256), 0, stream>>>(
        dec_o, mW1, mb1, mW2, mb2, cW1, cb1, cW2, cb2, outp);
}

// Round 4
// 363.259 us; speedup vs baseline: 1.0316x; 1.0316x over previous
//
#include <hip/hip_runtime.h>
#include <cstdint>
#include <cstddef>

// Problem constants (match reference)
#define BTOT    4096
#define SRCLEN  128
#define INDIM   16
#define HDIM    64
#define SEQLEN  100
#define MEANS_N (BTOT * SEQLEN * 4)   // 1638400

// ---------- helpers ----------
__device__ __forceinline__ float sigmoidf_(float x) {
    return __builtin_amdgcn_rcpf(1.0f + __expf(-x));
}
__device__ __forceinline__ float tanhf_(float x) {
    float e = __expf(2.0f * x);
    return 1.0f - 2.0f * __builtin_amdgcn_rcpf(e + 1.0f);
}
// gelu via Abramowitz-Stegun 7.1.26 erf (|err| < 1.5e-7)
__device__ __forceinline__ float gelu_fast(float x) {
    float z = fabsf(x) * 0.70710678118654752440f;
    float t = __builtin_amdgcn_rcpf(1.0f + 0.3275911f * z);
    float p = t * (0.254829592f +
              t * (-0.284496736f +
              t * (1.421413741f +
              t * (-1.453152027f +
              t * 1.061405429f))));
    float er = 1.0f - p * __expf(-z * z);
    er = copysignf(er, x);
    return 0.5f * x * (1.0f + er);
}

// ---------- bf16 split helpers (bf16x3 emulated-fp32 MFMA) ----------
typedef __attribute__((ext_vector_type(8))) short s8v;   // 8 bf16 (4 VGPRs)
typedef __attribute__((ext_vector_type(4))) float f4v;   // 4 fp32

__device__ __forceinline__ unsigned short f2bf(float x) {  // RTNE float -> bf16 bits
    unsigned u = __float_as_uint(x);
    unsigned r = (u + 0x7FFFu + ((u >> 16) & 1u)) >> 16;
    return (unsigned short)r;
}
__device__ __forceinline__ float bf2f(unsigned short b) {
    return __uint_as_float(((unsigned)b) << 16);
}
__device__ __forceinline__ void split2(float4 a, float4 b, s8v& hi, s8v& lo) {
    float v[8] = {a.x, a.y, a.z, a.w, b.x, b.y, b.z, b.w};
    #pragma unroll
    for (int j = 0; j < 8; ++j) {
        unsigned short h = f2bf(v[j]);
        hi[j] = (short)h;
        lo[j] = (short)f2bf(v[j] - bf2f(h));
    }
}
__device__ __forceinline__ void split8(const float* v, s8v& hi, s8v& lo) {
    #pragma unroll
    for (int j = 0; j < 8; ++j) {
        unsigned short h = f2bf(v[j]);
        hi[j] = (short)h;
        lo[j] = (short)f2bf(v[j] - bf2f(h));
    }
}
__device__ __forceinline__ void load_bfrag(const float* p, s8v& hi, s8v& lo) {
    float4 a = *(const float4*)p;
    float4 b = *(const float4*)(p + 4);
    split2(a, b, hi, lo);
}

// permlane32_swap merge (used by decoder's 8-batch rebalance)
typedef __attribute__((ext_vector_type(2))) unsigned int u2v;
__device__ __forceinline__ float half_merge(float own_lo, float send_hi) {
    u2v r = __builtin_amdgcn_permlane32_swap(__float_as_uint(own_lo),
                                             __float_as_uint(send_hi),
                                             false, false);
    return __uint_as_float(r[0]);
}

#define MFMA16(a, b, c) __builtin_amdgcn_mfma_f32_16x16x32_bf16((a), (b), (c), 0, 0, 0)

// =====================================================================
// Encoder GRU v2: 16 batches/block (M=16 tile FULL), 256 blocks, 512
// threads = 8 waves = 2/SIMD. Gate-split wave pairs: pair p = (wave p
// [role A], wave p+4 [role B]) owns units [p*16, p*16+16).
//   role A: r (9 MFMA) + h-part of n (6 MFMA), then activation + h-write
//   role B: z (9 MFMA) + x-part of n (3 MFMA), posts raw z/nx via LDS
// Per SIMD per step: 27 MFMA (was 54 in the 8-batch layout). No
// permlane merge needed (C rows = batches directly).
// =====================================================================
__global__ __launch_bounds__(512, 2) void enc_mfma_kernel(
    const float* __restrict__ x,
    const float* __restrict__ Wih, const float* __restrict__ bih,
    const float* __restrict__ Whh, const float* __restrict__ bhh,
    float* __restrict__ enc_h)
{
    const int tid  = threadIdx.x;
    const int lane = tid & 63;
    const int w    = tid >> 6;       // 0..7
    const int p    = w & 3;          // pair id
    const bool isA = (w < 4);
    const int col  = lane & 15;
    const int q    = lane >> 4;
    const int u    = p * 16 + col;   // h-unit
    const int b0   = blockIdx.x * 16;

    __shared__ __align__(16) unsigned short hiL[2][16][72];
    __shared__ __align__(16) unsigned short loL[2][16][72];
    // x chunk of 32 steps; batch rows 0..15 + zero row 16 (for k>=16 lanes)
    __shared__ __align__(16) unsigned short xhi_l[32][17][16];
    __shared__ __align__(16) unsigned short xlo_l[32][17][16];
    // pair exchange: [pair][slot 0..3 = z, 4..7 = nx][lane] (conflict-free SoA)
    __shared__ float zx_l[4][8][64];

    // zero h double-buffers (h0 = 0) and x pad row
    for (int i = tid; i < 2 * 16 * 72; i += 512) {
        ((unsigned short*)hiL)[i] = 0;
        ((unsigned short*)loL)[i] = 0;
    }
    for (int i = tid; i < 32 * 16; i += 512) {
        xhi_l[i >> 4][16][i & 15] = 0;
        xlo_l[i >> 4][16][i & 15] = 0;
    }

    // stage one 32-step chunk of x, pre-split into bf16 hi/lo
    auto stage_x = [&](int c) {
        #pragma unroll
        for (int k = 0; k < 4; ++k) {
            int f   = tid + k * 512;          // float4 idx in chunk (0..2047)
            int b   = f >> 7;                 // batch 0..15 (128 float4/batch)
            int rem = f & 127;
            int tl  = rem >> 2;               // local t 0..31
            int d4  = (rem & 3) << 2;         // dim 0,4,8,12
            const float* xp = x + ((size_t)(b0 + b) * SRCLEN + (c * 32 + tl)) * INDIM + d4;
            float4 v = *(const float4*)xp;
            float vv[4] = {v.x, v.y, v.z, v.w};
            unsigned short hh[4], ll[4];
            #pragma unroll
            for (int j = 0; j < 4; ++j) {
                hh[j] = f2bf(vv[j]);
                ll[j] = f2bf(vv[j] - bf2f(hh[j]));
            }
            *(ushort4*)&xhi_l[tl][b][d4] = make_ushort4(hh[0], hh[1], hh[2], hh[3]);
            *(ushort4*)&xlo_l[tl][b][d4] = make_ushort4(ll[0], ll[1], ll[2], ll[3]);
        }
    };

    const s8v z8 = {0, 0, 0, 0, 0, 0, 0, 0};
    const f4v z4 = {0.0f, 0.0f, 0.0f, 0.0f};

    // gate1 = r (role A) or z (role B); gate2 = n_h (role A) or n_x (role B)
    const int g1row = (isA ? 0 : 64) + u;     // Whh/Wih row for gate1
    s8v g1h[3], g1l[3];                        // [0],[1]: Whh k-chunks; [2]: Wih
    s8v g2h[2], g2l[2];
    load_bfrag(Whh + (size_t)g1row * 64 + q * 8,      g1h[0], g1l[0]);
    load_bfrag(Whh + (size_t)g1row * 64 + 32 + q * 8, g1h[1], g1l[1]);
    if (q < 2) load_bfrag(Wih + (size_t)g1row * 16 + q * 8, g1h[2], g1l[2]);
    else { g1h[2] = z8; g1l[2] = z8; }
    if (isA) {   // n_h: Whh row 128+u, both k-chunks
        load_bfrag(Whh + (size_t)(128 + u) * 64 + q * 8,      g2h[0], g2l[0]);
        load_bfrag(Whh + (size_t)(128 + u) * 64 + 32 + q * 8, g2h[1], g2l[1]);
    } else {     // n_x: Wih row 128+u (k<16 only)
        if (q < 2) load_bfrag(Wih + (size_t)(128 + u) * 16 + q * 8, g2h[0], g2l[0]);
        else { g2h[0] = z8; g2l[0] = z8; }
        g2h[1] = z8; g2l[1] = z8;
    }

    // biases (used by role A)
    const float br  = bih[u] + bhh[u];
    const float bz  = bih[u + 64] + bhh[u + 64];
    const float bnx = bih[u + 128];
    const float bnh = bhh[u + 128];

    // x A-frag base: lanes with k>=16 (q>=2) broadcast-read zero row 16
    const int xb   = (q < 2) ? col : 16;
    const int xoff = (q & 1) * 8;
    const unsigned short* xh_base = &xhi_l[0][xb][xoff];
    const unsigned short* xl_base = &xlo_l[0][xb][xoff];

    stage_x(0);
    float hold4[4] = {0.0f, 0.0f, 0.0f, 0.0f};
    __syncthreads();

    int cur = 0;
    for (int t = 0; t < SRCLEN; ++t) {
        const int tl = t & 31;
        if (t && tl == 0) {          // all reads of prev chunk done (barrier2)
            stage_x(t >> 5);
            __syncthreads();
        }

        const s8v xh = *(const s8v*)(xh_base + (size_t)tl * 272);  // 17*16
        const s8v xl = *(const s8v*)(xl_base + (size_t)tl * 272);

        const s8v ah0 = *(const s8v*)&hiL[cur][col][q * 8];
        const s8v al0 = *(const s8v*)&loL[cur][col][q * 8];
        const s8v ah1 = *(const s8v*)&hiL[cur][col][32 + q * 8];
        const s8v al1 = *(const s8v*)&loL[cur][col][32 + q * 8];

        // gate1 (r or z): 9 MFMAs, uniform across roles
        f4v a1;
        a1 = MFMA16(ah0, g1h[0], z4);
        a1 = MFMA16(ah0, g1l[0], a1);
        a1 = MFMA16(al0, g1h[0], a1);
        a1 = MFMA16(ah1, g1h[1], a1);
        a1 = MFMA16(ah1, g1l[1], a1);
        a1 = MFMA16(al1, g1h[1], a1);
        a1 = MFMA16(xh,  g1h[2], a1);
        a1 = MFMA16(xh,  g1l[2], a1);
        a1 = MFMA16(xl,  g1h[2], a1);

        f4v a2;
        if (isA) {   // n_h: 6 MFMAs
            a2 = MFMA16(ah0, g2h[0], z4);
            a2 = MFMA16(ah0, g2l[0], a2);
            a2 = MFMA16(al0, g2h[0], a2);
            a2 = MFMA16(ah1, g2h[1], a2);
            a2 = MFMA16(ah1, g2l[1], a2);
            a2 = MFMA16(al1, g2h[1], a2);
        } else {     // n_x: 3 MFMAs; post raw z & nx for role A
            a2 = MFMA16(xh, g2h[0], z4);
            a2 = MFMA16(xh, g2l[0], a2);
            a2 = MFMA16(xl, g2h[0], a2);
            #pragma unroll
            for (int i = 0; i < 4; ++i) {
                zx_l[p][i][lane]     = a1[i];
                zx_l[p][4 + i][lane] = a2[i];
            }
        }
        __syncthreads();   // barrier1: zx posted

        if (isA) {
            const int nxt = cur ^ 1;
            #pragma unroll
            for (int i = 0; i < 4; ++i) {
                float zz = sigmoidf_(zx_l[p][i][lane] + bz);
                float nx = zx_l[p][4 + i][lane] + bnx;
                float r  = sigmoidf_(a1[i] + br);
                float n  = tanhf_(nx + r * (a2[i] + bnh));
                float h  = (1.0f - zz) * n + zz * hold4[i];
                hold4[i] = h;
                unsigned short hh = f2bf(h);
                hiL[nxt][q * 4 + i][u] = hh;
                loL[nxt][q * 4 + i][u] = f2bf(h - bf2f(hh));
            }
        }
        __syncthreads();   // barrier2: h(nxt) complete
        cur ^= 1;
    }

    if (isA) {
        #pragma unroll
        for (int i = 0; i < 4; ++i)
            enc_h[(size_t)(b0 + q * 4 + i) * HDIM + u] = hold4[i];
    }
}

// =====================================================================
// Decoder GRU via MFMA with out-projection folded into the recurrence.
// (unchanged from R2 — pending port to the v2 structure once enc-v2
// verifies)
// =====================================================================
__global__ __launch_bounds__(256, 2) void dec_mfma_kernel(
    const float* __restrict__ trg,
    const float* __restrict__ Wih, const float* __restrict__ bih,
    const float* __restrict__ Whh, const float* __restrict__ bhh,
    const float* __restrict__ outW, const float* __restrict__ outb,
    const float* __restrict__ embW, const float* __restrict__ embb,
    const float* __restrict__ enc_h,
    float* __restrict__ dec_o)
{
    const int tid  = threadIdx.x;
    const int lane = tid & 63;
    const int w    = tid >> 6;
    const int col  = lane & 15;
    const int q    = lane >> 4;
    const int u    = w * 16 + col;
    const int b0   = blockIdx.x * 8;
    const int rj0  = (q & 1) * 4 + ((q >> 1) << 1);

    __shared__ __align__(16) unsigned short hiL[2][16][72];
    __shared__ __align__(16) unsigned short loL[2][16][72];
    __shared__ float outW_l[16][64];
    __shared__ float init_l[8][16];

    for (int i = tid; i < 16 * 64; i += 256) outW_l[i >> 6][i & 63] = outW[i];
    if (tid < 128) {
        int b = tid >> 4, jj = tid & 15;
        float s = embb[jj];
        #pragma unroll
        for (int s4 = 0; s4 < 4; ++s4)
            s = fmaf(embW[jj * 4 + s4], trg[(size_t)(b0 + b) * 4 + s4], s);
        init_l[b][jj] = s;
    }
    for (int i = tid; i < 2 * 8 * 72; i += 256) {
        int buf = i / (8 * 72);
        int rr  = (i / 72) & 7;
        int cc  = i % 72;
        hiL[buf][8 + rr][cc] = 0;
        loL[buf][8 + rr][cc] = 0;
    }
    if (tid < 128) {
        int idx = tid * 4;
        int bb = idx >> 6, uu = idx & 63;
        float4 v = *(const float4*)(enc_h + (size_t)(b0 + bb) * HDIM + uu);
        float vv[4] = {v.x, v.y, v.z, v.w};
        #pragma unroll
        for (int j = 0; j < 4; ++j) {
            unsigned short hh = f2bf(vv[j]);
            hiL[0][bb][uu + j] = hh;
            loL[0][bb][uu + j] = f2bf(vv[j] - bf2f(hh));
        }
    }
    float hold2[2];
    hold2[0] = enc_h[(size_t)(b0 + rj0) * HDIM + u];
    hold2[1] = enc_h[(size_t)(b0 + rj0 + 1) * HDIM + u];

    __syncthreads();

    const f4v z4 = {0.0f, 0.0f, 0.0f, 0.0f};

    float wh_r[16], wh_z[16], wh_n[16];
    #pragma unroll
    for (int c = 0; c < 2; ++c)
        #pragma unroll
        for (int jj = 0; jj < 8; ++jj) {
            int k = c * 32 + q * 8 + jj;
            wh_r[c * 8 + jj] = Whh[(size_t)u * 64 + k];
            wh_z[c * 8 + jj] = Whh[(size_t)(64 + u) * 64 + k];
            wh_n[c * 8 + jj] = Whh[(size_t)(128 + u) * 64 + k];
        }
    float wi_r[16], wi_z[16], wi_n[16];
    #pragma unroll
    for (int j = 0; j < 16; ++j) {
        wi_r[j] = Wih[(size_t)u * 16 + j];
        wi_z[j] = Wih[(size_t)(64 + u) * 16 + j];
        wi_n[j] = Wih[(size_t)(128 + u) * 16 + j];
    }

    float m_r[16], m_z[16], c_in[16];
    #pragma unroll
    for (int c = 0; c < 2; ++c)
        #pragma unroll
        for (int jj = 0; jj < 8; ++jj) {
            int k = c * 32 + q * 8 + jj;
            float sr = 0.0f, sz = 0.0f, sn = 0.0f;
            #pragma unroll
            for (int j = 0; j < 16; ++j) {
                float ow = outW_l[j][k];
                sr = fmaf(wi_r[j], ow, sr);
                sz = fmaf(wi_z[j], ow, sz);
                sn = fmaf(wi_n[j], ow, sn);
            }
            m_r[c * 8 + jj]  = wh_r[c * 8 + jj] + sr;
            m_z[c * 8 + jj]  = wh_z[c * 8 + jj] + sz;
            c_in[c * 8 + jj] = sn;
        }

    s8v mrh[2], mrl[2], mzh[2], mzl[2], cinh[2], cinl[2], hnh[2], hnl[2];
    split8(m_r,      mrh[0],  mrl[0]);  split8(m_r + 8,  mrh[1],  mrl[1]);
    split8(m_z,      mzh[0],  mzl[0]);  split8(m_z + 8,  mzh[1],  mzl[1]);
    split8(c_in,     cinh[0], cinl[0]); split8(c_in + 8, cinh[1], cinl[1]);
    split8(wh_n,     hnh[0],  hnl[0]);  split8(wh_n + 8, hnh[1],  hnl[1]);
    s8v r0h[2], r0l[2], z0h[2], z0l[2];
    split8(wh_r, r0h[0], r0l[0]); split8(wh_r + 8, r0h[1], r0l[1]);
    split8(wh_z, z0h[0], z0l[0]); split8(wh_z + 8, z0h[1], z0l[1]);
    s8v owh[2], owl[2];
    {
        float ov[16];
        #pragma unroll
        for (int c = 0; c < 2; ++c)
            #pragma unroll
            for (int jj = 0; jj < 8; ++jj)
                ov[c * 8 + jj] = outW_l[col][c * 32 + q * 8 + jj];
        split8(ov, owh[0], owl[0]); split8(ov + 8, owh[1], owl[1]);
    }

    float b_r = bhh[u] + bih[u];
    float b_z = bhh[u + 64] + bih[u + 64];
    float b_in = bih[u + 128];
    const float b_hn = bhh[u + 128];
    #pragma unroll
    for (int j = 0; j < 16; ++j) {
        float obj = outb[j];
        b_r  = fmaf(obj, wi_r[j], b_r);
        b_z  = fmaf(obj, wi_z[j], b_z);
        b_in = fmaf(obj, wi_n[j], b_in);
    }
    const float ob = outb[col];

    float g_r[2], g_z[2], g_n[2];
    #pragma unroll
    for (int j2 = 0; j2 < 2; ++j2) {
        int row = rj0 + j2;
        float sr = bih[u] + bhh[u];
        float sz = bih[u + 64] + bhh[u + 64];
        float sn = bih[u + 128];
        #pragma unroll
        for (int j = 0; j < 16; ++j) {
            float iv = init_l[row][j];
            sr = fmaf(wi_r[j], iv, sr);
            sz = fmaf(wi_z[j], iv, sz);
            sn = fmaf(wi_n[j], iv, sn);
        }
        g_r[j2] = sr; g_z[j2] = sz; g_n[j2] = sn;
    }

    {
        const s8v ah0 = *(const s8v*)&hiL[0][col][q * 8];
        const s8v al0 = *(const s8v*)&loL[0][col][q * 8];
        const s8v ah1 = *(const s8v*)&hiL[0][col][32 + q * 8];
        const s8v al1 = *(const s8v*)&loL[0][col][32 + q * 8];
        f4v ar, az, ahn;
        ar  = MFMA16(ah0, r0h[0], z4);
        az  = MFMA16(ah0, z0h[0], z4);
        ahn = MFMA16(ah0, hnh[0], z4);
        ar  = MFMA16(ah0, r0l[0], ar);
        az  = MFMA16(ah0, z0l[0], az);
        ahn = MFMA16(ah0, hnl[0], ahn);
        ar  = MFMA16(al0, r0h[0], ar);
        az  = MFMA16(al0, z0h[0], az);
        ahn = MFMA16(al0, hnh[0], ahn);
        ar  = MFMA16(ah1, r0h[1], ar);
        az  = MFMA16(ah1, z0h[1], az);
        ahn = MFMA16(ah1, hnh[1], ahn);
        ar  = MFMA16(ah1, r0l[1], ar);
        az  = MFMA16(ah1, z0l[1], az);
        ahn = MFMA16(ah1, hnl[1], ahn);
        ar  = MFMA16(al1, r0h[1], ar);
        az  = MFMA16(al1, z0h[1], az);
        ahn = MFMA16(al1, hnh[1], ahn);

        float pr[2], pz[2], pnh[2];
        pr[0]  = half_merge(ar[0],  ar[2]);
        pr[1]  = half_merge(ar[1],  ar[3]);
        pz[0]  = half_merge(az[0],  az[2]);
        pz[1]  = half_merge(az[1],  az[3]);
        pnh[0] = half_merge(ahn[0], ahn[2]);
        pnh[1] = half_merge(ahn[1], ahn[3]);

        #pragma unroll
        for (int j = 0; j < 2; ++j) {
            float r  = sigmoidf_(pr[j] + g_r[j]);
            float zz = sigmoidf_(pz[j] + g_z[j]);
            float n  = tanhf_(g_n[j] + r * (pnh[j] + b_hn));
            float h  = (1.0f - zz) * n + zz * hold2[j];
            hold2[j] = h;
            unsigned short hh = f2bf(h);
            hiL[1][rj0 + j][u] = hh;
            loL[1][rj0 + j][u] = f2bf(h - bf2f(hh));
        }
        __syncthreads();
    }

    for (int t = 1; t < SEQLEN; ++t) {
        const int cur = t & 1;
        const s8v ah0 = *(const s8v*)&hiL[cur][col][q * 8];
        const s8v al0 = *(const s8v*)&loL[cur][col][q * 8];
        const s8v ah1 = *(const s8v*)&hiL[cur][col][32 + q * 8];
        const s8v al1 = *(const s8v*)&loL[cur][col][32 + q * 8];

        if (w == ((t - 1) & 3)) {
            f4v oa;
            oa = MFMA16(ah0, owh[0], z4);
            oa = MFMA16(ah0, owl[0], oa);
            oa = MFMA16(al0, owh[0], oa);
            oa = MFMA16(ah1, owh[1], oa);
            oa = MFMA16(ah1, owl[1], oa);
            oa = MFMA16(al1, owh[1], oa);
            if (q < 2) {
                #pragma unroll
                for (int i = 0; i < 4; ++i)
                    dec_o[(((size_t)(b0 + q * 4 + i) * SEQLEN) + (t - 1)) * INDIM + col] = oa[i] + ob;
            }
        }

        f4v ar, az, ain, ahn;
        ar  = MFMA16(ah0, mrh[0], z4);
        az  = MFMA16(ah0, mzh[0], z4);
        ain = MFMA16(ah0, cinh[0], z4);
        ahn = MFMA16(ah0, hnh[0], z4);
        ar  = MFMA16(ah0, mrl[0], ar);
        az  = MFMA16(ah0, mzl[0], az);
        ain = MFMA16(ah0, cinl[0], ain);
        ahn = MFMA16(ah0, hnl[0], ahn);
        ar  = MFMA16(al0, mrh[0], ar);
        az  = MFMA16(al0, mzh[0], az);
        ain = MFMA16(al0, cinh[0], ain);
        ahn = MFMA16(al0, hnh[0], ahn);
        ar  = MFMA16(ah1, mrh[1], ar);
        az  = MFMA16(ah1, mzh[1], az);
        ain = MFMA16(ah1, cinh[1], ain);
        ahn = MFMA16(ah1, hnh[1], ahn);
        ar  = MFMA16(ah1, mrl[1], ar);
        az  = MFMA16(ah1, mzl[1], az);
        ain = MFMA16(ah1, cinl[1], ain);
        ahn = MFMA16(ah1, hnl[1], ahn);
        ar  = MFMA16(al1, mrh[1], ar);
        az  = MFMA16(al1, mzh[1], az);
        ain = MFMA16(al1, cinh[1], ain);
        ahn = MFMA16(al1, hnh[1], ahn);

        float pr[2], pz[2], pin[2], pnh[2];
        pr[0]  = half_merge(ar[0],  ar[2]);
        pr[1]  = half_merge(ar[1],  ar[3]);
        pz[0]  = half_merge(az[0],  az[2]);
        pz[1]  = half_merge(az[1],  az[3]);
        pin[0] = half_merge(ain[0], ain[2]);
        pin[1] = half_merge(ain[1], ain[3]);
        pnh[0] = half_merge(ahn[0], ahn[2]);
        pnh[1] = half_merge(ahn[1], ahn[3]);

        const int nxt = cur ^ 1;
        #pragma unroll
        for (int j = 0; j < 2; ++j) {
            float r  = sigmoidf_(pr[j] + b_r);
            float zz = sigmoidf_(pz[j] + b_z);
            float n  = tanhf_(pin[j] + b_in + r * (pnh[j] + b_hn));
            float h  = (1.0f - zz) * n + zz * hold2[j];
            hold2[j] = h;
            unsigned short hh = f2bf(h);
            hiL[nxt][rj0 + j][u] = hh;
            loL[nxt][rj0 + j][u] = f2bf(h - bf2f(hh));
        }
        __syncthreads();
    }

    if (w == 0) {
        const s8v ah0 = *(const s8v*)&hiL[0][col][q * 8];
        const s8v al0 = *(const s8v*)&loL[0][col][q * 8];
        const s8v ah1 = *(const s8v*)&hiL[0][col][32 + q * 8];
        const s8v al1 = *(const s8v*)&loL[0][col][32 + q * 8];
        f4v oa;
        oa = MFMA16(ah0, owh[0], z4);
        oa = MFMA16(ah0, owl[0], oa);
        oa = MFMA16(al0, owh[0], oa);
        oa = MFMA16(ah1, owh[1], oa);
        oa = MFMA16(ah1, owl[1], oa);
        oa = MFMA16(al1, owh[1], oa);
        if (q < 2) {
            #pragma unroll
            for (int i = 0; i < 4; ++i)
                dec_o[(((size_t)(b0 + q * 4 + i) * SEQLEN) + (SEQLEN - 1)) * INDIM + col] = oa[i] + ob;
        }
    }
}

// =====================================================================
// Heads: reverted byte-for-byte to the R2 version (1 row/thread, LDS
// weights, 1600 blocks) — the R3 4-row variant regressed total by 27 µs.
// =====================================================================
__global__ __launch_bounds__(256) void heads_kernel(
    const float* __restrict__ dec_o,
    const float* __restrict__ mW1, const float* __restrict__ mb1,
    const float* __restrict__ mW2, const float* __restrict__ mb2,
    const float* __restrict__ cW1, const float* __restrict__ cb1,
    const float* __restrict__ cW2, const float* __restrict__ cb2,
    float* __restrict__ out)
{
    const int tid = threadIdx.x;

    __shared__ __align__(16) float lW1m[64][16];
    __shared__ __align__(16) float lW1c[64][16];
    __shared__ __align__(16) float lW2t[64][16];

    for (int i = tid; i < 1024; i += 256) {
        lW1m[i >> 4][i & 15] = mW1[i];
        lW1c[i >> 4][i & 15] = cW1[i];
    }
    if (tid < 64) {
        #pragma unroll
        for (int j = 0; j < 4; ++j)  lW2t[tid][j]     = mW2[j * 64 + tid];
        #pragma unroll
        for (int j = 0; j < 10; ++j) lW2t[tid][4 + j] = cW2[j * 64 + tid];
        lW2t[tid][14] = mb1[tid];
        lW2t[tid][15] = cb1[tid];
    }
    __syncthreads();

    const size_t r = (size_t)blockIdx.x * 256 + tid;

    float o16[16];
    {
        const float4* op = (const float4*)(dec_o + r * 16);
        #pragma unroll
        for (int c = 0; c < 4; ++c) {
            float4 v = op[c];
            o16[4 * c + 0] = v.x; o16[4 * c + 1] = v.y;
            o16[4 * c + 2] = v.z; o16[4 * c + 3] = v.w;
        }
    }

    float m[4], cv[10];
    #pragma unroll
    for (int j = 0; j < 4; ++j)  m[j]  = mb2[j];
    #pragma unroll
    for (int j = 0; j < 10; ++j) cv[j] = cb2[j];

    #pragma unroll 4
    for (int hu = 0; hu < 64; ++hu) {
        const float4 a0 = *(const float4*)&lW1m[hu][0];
        const float4 a1 = *(const float4*)&lW1m[hu][4];
        const float4 a2 = *(const float4*)&lW1m[hu][8];
        const float4 a3 = *(const float4*)&lW1m[hu][12];
        const float4 c0 = *(const float4*)&lW1c[hu][0];
        const float4 c1 = *(const float4*)&lW1c[hu][4];
        const float4 c2 = *(const float4*)&lW1c[hu][8];
        const float4 c3 = *(const float4*)&lW1c[hu][12];
        const float4 t0 = *(const float4*)&lW2t[hu][0];
        const float4 t1 = *(const float4*)&lW2t[hu][4];
        const float4 t2 = *(const float4*)&lW2t[hu][8];
        const float4 t3 = *(const float4*)&lW2t[hu][12];

        float hm = t3.z;  // mb1[hu]
        hm = fmaf(a0.x, o16[0],  hm); hm = fmaf(a0.y, o16[1],  hm);
        hm = fmaf(a0.z, o16[2],  hm); hm = fmaf(a0.w, o16[3],  hm);
        hm = fmaf(a1.x, o16[4],  hm); hm = fmaf(a1.y, o16[5],  hm);
        hm = fmaf(a1.z, o16[6],  hm); hm = fmaf(a1.w, o16[7],  hm);
        hm = fmaf(a2.x, o16[8],  hm); hm = fmaf(a2.y, o16[9],  hm);
        hm = fmaf(a2.z, o16[10], hm); hm = fmaf(a2.w, o16[11], hm);
        hm = fmaf(a3.x, o16[12], hm); hm = fmaf(a3.y, o16[13], hm);
        hm = fmaf(a3.z, o16[14], hm); hm = fmaf(a3.w, o16[15], hm);
        float gm = gelu_fast(hm);
        m[0] = fmaf(t0.x, gm, m[0]); m[1] = fmaf(t0.y, gm, m[1]);
        m[2] = fmaf(t0.z, gm, m[2]); m[3] = fmaf(t0.w, gm, m[3]);

        float hc = t3.w;  // cb1[hu]
        hc = fmaf(c0.x, o16[0],  hc); hc = fmaf(c0.y, o16[1],  hc);
        hc = fmaf(c0.z, o16[2],  hc); hc = fmaf(c0.w, o16[3],  hc);
        hc = fmaf(c1.x, o16[4],  hc); hc = fmaf(c1.y, o16[5],  hc);
        hc = fmaf(c1.z, o16[6],  hc); hc = fmaf(c1.w, o16[7],  hc);
        hc = fmaf(c2.x, o16[8],  hc); hc = fmaf(c2.y, o16[9],  hc);
        hc = fmaf(c2.z, o16[10], hc); hc = fmaf(c2.w, o16[11], hc);
        hc = fmaf(c3.x, o16[12], hc); hc = fmaf(c3.y, o16[13], hc);
        hc = fmaf(c3.z, o16[14], hc); hc = fmaf(c3.w, o16[15], hc);
        float gc = gelu_fast(hc);
        cv[0] = fmaf(t1.x, gc, cv[0]); cv[1] = fmaf(t1.y, gc, cv[1]);
        cv[2] = fmaf(t1.z, gc, cv[2]); cv[3] = fmaf(t1.w, gc, cv[3]);
        cv[4] = fmaf(t2.x, gc, cv[4]); cv[5] = fmaf(t2.y, gc, cv[5]);
        cv[6] = fmaf(t2.z, gc, cv[6]); cv[7] = fmaf(t2.w, gc, cv[7]);
        cv[8] = fmaf(t3.x, gc, cv[8]); cv[9] = fmaf(t3.y, gc, cv[9]);
    }

    m[2] = fminf(fmaxf(m[2], -1.0f), 1.0f);
    m[3] = fminf(fmaxf(m[3], -1.0f), 1.0f);

    float* means = out;
    float* covs  = out + MEANS_N;
    #pragma unroll
    for (int j = 0; j < 4; ++j)  means[r * 4 + j]  = m[j];
    #pragma unroll
    for (int j = 0; j < 10; ++j) covs[r * 10 + j]  = cv[j];
}

// =====================================================================
extern "C" void kernel_launch(void* const* d_in, const int* in_sizes, int n_in,
                              void* d_out, int out_size, void* d_ws, size_t ws_size,
                              hipStream_t stream)
{
    const float* x    = (const float*)d_in[0];
    const float* trg  = (const float*)d_in[1];
    const float* eWih = (const float*)d_in[2];
    const float* ebih = (const float*)d_in[3];
    const float* eWhh = (const float*)d_in[4];
    const float* ebhh = (const float*)d_in[5];
    const float* dWih = (const float*)d_in[6];
    const float* dbih = (const float*)d_in[7];
    const float* dWhh = (const float*)d_in[8];
    const float* dbhh = (const float*)d_in[9];
    const float* outW = (const float*)d_in[10];
    const float* outb = (const float*)d_in[11];
    const float* embW = (const float*)d_in[12];
    const float* embb = (const float*)d_in[13];
    const float* mW1  = (const float*)d_in[14];
    const float* mb1  = (const float*)d_in[15];
    const float* mW2  = (const float*)d_in[16];
    const float* mb2  = (const float*)d_in[17];
    const float* cW1  = (const float*)d_in[18];
    const float* cb1  = (const float*)d_in[19];
    const float* cW2  = (const float*)d_in[20];
    const float* cb2  = (const float*)d_in[21];

    float* ws    = (float*)d_ws;
    float* enc_h = ws;                          // 4096*64      = 262144 floats
    float* dec_o = ws + (size_t)BTOT * HDIM;    // 4096*100*16  = 6553600 floats
    float* outp  = (float*)d_out;

    enc_mfma_kernel<<<dim3(BTOT / 16), dim3(512), 0, stream>>>(x, eWih, ebih, eWhh, ebhh, enc_h);
    dec_mfma_kernel<<<dim3(BTOT / 8), dim3(256), 0, stream>>>(trg, dWih, dbih, dWhh, dbhh,
                                                              outW, outb, embW, embb, enc_h, dec_o);
    heads_kernel<<<dim3((BTOT * SEQLEN) / 256), dim3(256), 0, stream>>>(
        dec_o, mW1, mb1, mW2, mb2, cW1, cb1, cW2, cb2, outp);
}

// Round 5
// 358.437 us; speedup vs baseline: 1.0455x; 1.0135x over previous
//
#include <hip/hip_runtime.h>
#include <cstdint>
#include <cstddef>

// Problem constants (match reference)
#define BTOT    4096
#define SRCLEN  128
#define INDIM   16
#define HDIM    64
#define SEQLEN  100
#define MEANS_N (BTOT * SEQLEN * 4)   // 1638400

// ---------- helpers ----------
__device__ __forceinline__ float sigmoidf_(float x) {
    return __builtin_amdgcn_rcpf(1.0f + __expf(-x));
}
__device__ __forceinline__ float tanhf_(float x) {
    float e = __expf(2.0f * x);
    return 1.0f - 2.0f * __builtin_amdgcn_rcpf(e + 1.0f);
}
// gelu via Abramowitz-Stegun 7.1.26 erf (|err| < 1.5e-7)
__device__ __forceinline__ float gelu_fast(float x) {
    float z = fabsf(x) * 0.70710678118654752440f;
    float t = __builtin_amdgcn_rcpf(1.0f + 0.3275911f * z);
    float p = t * (0.254829592f +
              t * (-0.284496736f +
              t * (1.421413741f +
              t * (-1.453152027f +
              t * 1.061405429f))));
    float er = 1.0f - p * __expf(-z * z);
    er = copysignf(er, x);
    return 0.5f * x * (1.0f + er);
}

// ---------- bf16 split helpers (bf16x3 emulated-fp32 MFMA) ----------
typedef __attribute__((ext_vector_type(8))) short s8v;   // 8 bf16 (4 VGPRs)
typedef __attribute__((ext_vector_type(4))) float f4v;   // 4 fp32

__device__ __forceinline__ unsigned short f2bf(float x) {  // RTNE float -> bf16 bits
    unsigned u = __float_as_uint(x);
    unsigned r = (u + 0x7FFFu + ((u >> 16) & 1u)) >> 16;
    return (unsigned short)r;
}
__device__ __forceinline__ float bf2f(unsigned short b) {
    return __uint_as_float(((unsigned)b) << 16);
}
__device__ __forceinline__ void split2(float4 a, float4 b, s8v& hi, s8v& lo) {
    float v[8] = {a.x, a.y, a.z, a.w, b.x, b.y, b.z, b.w};
    #pragma unroll
    for (int j = 0; j < 8; ++j) {
        unsigned short h = f2bf(v[j]);
        hi[j] = (short)h;
        lo[j] = (short)f2bf(v[j] - bf2f(h));
    }
}
__device__ __forceinline__ void split8(const float* v, s8v& hi, s8v& lo) {
    #pragma unroll
    for (int j = 0; j < 8; ++j) {
        unsigned short h = f2bf(v[j]);
        hi[j] = (short)h;
        lo[j] = (short)f2bf(v[j] - bf2f(h));
    }
}
__device__ __forceinline__ void load_bfrag(const float* p, s8v& hi, s8v& lo) {
    float4 a = *(const float4*)p;
    float4 b = *(const float4*)(p + 4);
    split2(a, b, hi, lo);
}

// permlane32_swap merge: lanes 0-31 keep own_lo, lanes 32-63 get send_hi
// from lane-32. Single VALU op.
typedef __attribute__((ext_vector_type(2))) unsigned int u2v;
__device__ __forceinline__ float half_merge(float own_lo, float send_hi) {
    u2v r = __builtin_amdgcn_permlane32_swap(__float_as_uint(own_lo),
                                             __float_as_uint(send_hi),
                                             false, false);
    return __uint_as_float(r[0]);
}

#define MFMA16(a, b, c) __builtin_amdgcn_mfma_f32_16x16x32_bf16((a), (b), (c), 0, 0, 0)

// =====================================================================
// FUSED encoder + decoder GRU (R2-proven 8-batch structures for both).
// 512 blocks x 256 threads, 2 blocks/CU. The enc->dec handoff happens
// in-register (hold2) and in-LDS (hiL[0]/loL[0] already hold the split
// final enc h with the exact row/unit mapping dec uses): no enc_h HBM
// round-trip, no second launch, no global sync.
// =====================================================================
__global__ __launch_bounds__(256, 2) void fused_gru_kernel(
    const float* __restrict__ x,
    const float* __restrict__ eWih, const float* __restrict__ ebih,
    const float* __restrict__ eWhh, const float* __restrict__ ebhh,
    const float* __restrict__ dWih, const float* __restrict__ dbih,
    const float* __restrict__ dWhh, const float* __restrict__ dbhh,
    const float* __restrict__ outW, const float* __restrict__ outb,
    const float* __restrict__ embW, const float* __restrict__ embb,
    const float* __restrict__ trg,
    float* __restrict__ dec_o)
{
    const int tid  = threadIdx.x;
    const int lane = tid & 63;
    const int w    = tid >> 6;     // wave 0..3
    const int col  = lane & 15;
    const int q    = lane >> 4;
    const int u    = w * 16 + col;
    const int b0   = blockIdx.x * 8;
    // post-rebalance batch row for item j: rows {0,1},{4,5},{2,3},{6,7} for q=0..3
    const int rj0  = (q & 1) * 4 + ((q >> 1) << 1);

    __shared__ __align__(16) unsigned short hiL[2][16][72];
    __shared__ __align__(16) unsigned short loL[2][16][72];
    // enc x tile: [tl][batch 0..7 | zero-row 8][dim]
    __shared__ __align__(16) unsigned short xhi_l[64][9][16];
    __shared__ __align__(16) unsigned short xlo_l[64][9][16];
    // dec helpers (staged up front; read only after the first barrier)
    __shared__ float outW_l[16][64];
    __shared__ float init_l[8][16];

    // ---- stage dec LDS (outW, init_in) ----
    for (int i = tid; i < 16 * 64; i += 256) outW_l[i >> 6][i & 63] = outW[i];
    if (tid < 128) {
        int b = tid >> 4, jj = tid & 15;
        float s = embb[jj];
        #pragma unroll
        for (int s4 = 0; s4 < 4; ++s4)
            s = fmaf(embW[jj * 4 + s4], trg[(size_t)(b0 + b) * 4 + s4], s);
        init_l[b][jj] = s;
    }

    // ---- enc init: zero both h buffers (rows 8-15 stay zero forever) ----
    for (int i = tid; i < 2 * 16 * 72; i += 256) {
        ((unsigned short*)hiL)[i] = 0;
        ((unsigned short*)loL)[i] = 0;
    }
    for (int i = tid; i < 64 * 16; i += 256) {
        xhi_l[i >> 4][8][i & 15] = 0;
        xlo_l[i >> 4][8][i & 15] = 0;
    }

    // stage one 64-step chunk of x, pre-split into bf16 hi/lo
    auto stage_x = [&](int c) {
        #pragma unroll
        for (int k = 0; k < 8; ++k) {
            int f   = tid + k * 256;
            int b   = f >> 8;
            int rem = f & 255;
            int tl  = rem >> 2;
            int d4  = (rem & 3) << 2;
            const float* xp = x + ((size_t)(b0 + b) * SRCLEN + (c * 64 + tl)) * INDIM + d4;
            float4 v = *(const float4*)xp;
            float vv[4] = {v.x, v.y, v.z, v.w};
            unsigned short hh[4], ll[4];
            #pragma unroll
            for (int j = 0; j < 4; ++j) {
                hh[j] = f2bf(vv[j]);
                ll[j] = f2bf(vv[j] - bf2f(hh[j]));
            }
            *(ushort4*)&xhi_l[tl][b][d4] = make_ushort4(hh[0], hh[1], hh[2], hh[3]);
            *(ushort4*)&xlo_l[tl][b][d4] = make_ushort4(ll[0], ll[1], ll[2], ll[3]);
        }
    };

    const s8v z8 = {0, 0, 0, 0, 0, 0, 0, 0};
    const f4v z4 = {0.0f, 0.0f, 0.0f, 0.0f};

    // ================= ENCODER PHASE (R2-exact) =================
    {
        s8v brh[3], brl[3], bzh[3], bzl[3], bnhh[2], bnhl[2], bnxh, bnxl;
        load_bfrag(eWhh + (size_t)u * 64 + q * 8,              brh[0], brl[0]);
        load_bfrag(eWhh + (size_t)u * 64 + 32 + q * 8,         brh[1], brl[1]);
        load_bfrag(eWhh + (size_t)(64 + u) * 64 + q * 8,       bzh[0], bzl[0]);
        load_bfrag(eWhh + (size_t)(64 + u) * 64 + 32 + q * 8,  bzh[1], bzl[1]);
        load_bfrag(eWhh + (size_t)(128 + u) * 64 + q * 8,      bnhh[0], bnhl[0]);
        load_bfrag(eWhh + (size_t)(128 + u) * 64 + 32 + q * 8, bnhh[1], bnhl[1]);
        if (q < 2) {
            load_bfrag(eWih + (size_t)u * 16 + q * 8,         brh[2], brl[2]);
            load_bfrag(eWih + (size_t)(64 + u) * 16 + q * 8,  bzh[2], bzl[2]);
            load_bfrag(eWih + (size_t)(128 + u) * 16 + q * 8, bnxh, bnxl);
        } else {
            brh[2] = z8; brl[2] = z8; bzh[2] = z8; bzl[2] = z8; bnxh = z8; bnxl = z8;
        }

        const float br   = ebih[u] + ebhh[u];
        const float bz   = ebih[u + 64] + ebhh[u + 64];
        const float bnx  = ebih[u + 128];
        const float bnh  = ebhh[u + 128];

        const int xb   = (q < 2) ? (col & 7) : 8;
        const int xoff = (q & 1) * 8;
        const unsigned short* xh_base = &xhi_l[0][xb][xoff];
        const unsigned short* xl_base = &xlo_l[0][xb][xoff];

        stage_x(0);
        float hold2e[2] = {0.0f, 0.0f};
        __syncthreads();

        int cur = 0;
        for (int t = 0; t < SRCLEN; ++t) {
            if (t == 64) {
                stage_x(1);
                __syncthreads();
            }
            const int tl = t & 63;

            const s8v xh = *(const s8v*)(xh_base + (size_t)tl * 144);
            const s8v xl = *(const s8v*)(xl_base + (size_t)tl * 144);

            const s8v ah0 = *(const s8v*)&hiL[cur][col][q * 8];
            const s8v al0 = *(const s8v*)&loL[cur][col][q * 8];
            const s8v ah1 = *(const s8v*)&hiL[cur][col][32 + q * 8];
            const s8v al1 = *(const s8v*)&loL[cur][col][32 + q * 8];

            f4v accr, accz, accnh, accnx;
            accr  = MFMA16(ah0, brh[0], z4);
            accz  = MFMA16(ah0, bzh[0], z4);
            accnh = MFMA16(ah0, bnhh[0], z4);
            accr  = MFMA16(ah0, brl[0], accr);
            accz  = MFMA16(ah0, bzl[0], accz);
            accnh = MFMA16(ah0, bnhl[0], accnh);
            accr  = MFMA16(al0, brh[0], accr);
            accz  = MFMA16(al0, bzh[0], accz);
            accnh = MFMA16(al0, bnhh[0], accnh);
            accr  = MFMA16(ah1, brh[1], accr);
            accz  = MFMA16(ah1, bzh[1], accz);
            accnh = MFMA16(ah1, bnhh[1], accnh);
            accr  = MFMA16(ah1, brl[1], accr);
            accz  = MFMA16(ah1, bzl[1], accz);
            accnh = MFMA16(ah1, bnhl[1], accnh);
            accr  = MFMA16(al1, brh[1], accr);
            accz  = MFMA16(al1, bzh[1], accz);
            accnh = MFMA16(al1, bnhh[1], accnh);
            accr  = MFMA16(xh, brh[2], accr);
            accz  = MFMA16(xh, bzh[2], accz);
            accnx = MFMA16(xh, bnxh, z4);
            accr  = MFMA16(xh, brl[2], accr);
            accz  = MFMA16(xh, bzl[2], accz);
            accnx = MFMA16(xh, bnxl, accnx);
            accr  = MFMA16(xl, brh[2], accr);
            accz  = MFMA16(xl, bzh[2], accz);
            accnx = MFMA16(xl, bnxh, accnx);

            float pr[2], pz[2], pnh[2], pnx[2];
            pr[0]  = half_merge(accr[0],  accr[2]);
            pr[1]  = half_merge(accr[1],  accr[3]);
            pz[0]  = half_merge(accz[0],  accz[2]);
            pz[1]  = half_merge(accz[1],  accz[3]);
            pnh[0] = half_merge(accnh[0], accnh[2]);
            pnh[1] = half_merge(accnh[1], accnh[3]);
            pnx[0] = half_merge(accnx[0], accnx[2]);
            pnx[1] = half_merge(accnx[1], accnx[3]);

            const int nxt = cur ^ 1;
            #pragma unroll
            for (int j = 0; j < 2; ++j) {
                float r  = sigmoidf_(pr[j] + br);
                float zz = sigmoidf_(pz[j] + bz);
                float n  = tanhf_(pnx[j] + bnx + r * (pnh[j] + bnh));
                float h  = (1.0f - zz) * n + zz * hold2e[j];
                hold2e[j] = h;
                unsigned short hh = f2bf(h);
                hiL[nxt][rj0 + j][u] = hh;
                loL[nxt][rj0 + j][u] = f2bf(h - bf2f(hh));
            }
            __syncthreads();
            cur ^= 1;
        }
        // enc done: final h split is in hiL[0]/loL[0]; fp32 h in hold2e.
        // fall through to decoder with hold2 = hold2e.
        // (cur == 0 after 128 steps)

        // ================= DECODER PHASE (R2-exact minus h0 staging) =====
        float hold2[2] = {hold2e[0], hold2e[1]};

        // ---- dec prologue (register-only; LDS outW_l/init_l staged up top) ----
        float wh_r[16], wh_z[16], wh_n[16];
        #pragma unroll
        for (int c = 0; c < 2; ++c)
            #pragma unroll
            for (int jj = 0; jj < 8; ++jj) {
                int k = c * 32 + q * 8 + jj;
                wh_r[c * 8 + jj] = dWhh[(size_t)u * 64 + k];
                wh_z[c * 8 + jj] = dWhh[(size_t)(64 + u) * 64 + k];
                wh_n[c * 8 + jj] = dWhh[(size_t)(128 + u) * 64 + k];
            }
        float wi_r[16], wi_z[16], wi_n[16];
        #pragma unroll
        for (int j = 0; j < 16; ++j) {
            wi_r[j] = dWih[(size_t)u * 16 + j];
            wi_z[j] = dWih[(size_t)(64 + u) * 16 + j];
            wi_n[j] = dWih[(size_t)(128 + u) * 16 + j];
        }

        float m_r[16], m_z[16], c_in[16];
        #pragma unroll
        for (int c = 0; c < 2; ++c)
            #pragma unroll
            for (int jj = 0; jj < 8; ++jj) {
                int k = c * 32 + q * 8 + jj;
                float sr = 0.0f, sz = 0.0f, sn = 0.0f;
                #pragma unroll
                for (int j = 0; j < 16; ++j) {
                    float ow = outW_l[j][k];
                    sr = fmaf(wi_r[j], ow, sr);
                    sz = fmaf(wi_z[j], ow, sz);
                    sn = fmaf(wi_n[j], ow, sn);
                }
                m_r[c * 8 + jj]  = wh_r[c * 8 + jj] + sr;
                m_z[c * 8 + jj]  = wh_z[c * 8 + jj] + sz;
                c_in[c * 8 + jj] = sn;
            }

        s8v mrh[2], mrl[2], mzh[2], mzl[2], cinh[2], cinl[2], hnh[2], hnl[2];
        split8(m_r,      mrh[0],  mrl[0]);  split8(m_r + 8,  mrh[1],  mrl[1]);
        split8(m_z,      mzh[0],  mzl[0]);  split8(m_z + 8,  mzh[1],  mzl[1]);
        split8(c_in,     cinh[0], cinl[0]); split8(c_in + 8, cinh[1], cinl[1]);
        split8(wh_n,     hnh[0],  hnl[0]);  split8(wh_n + 8, hnh[1],  hnl[1]);
        s8v r0h[2], r0l[2], z0h[2], z0l[2];
        split8(wh_r, r0h[0], r0l[0]); split8(wh_r + 8, r0h[1], r0l[1]);
        split8(wh_z, z0h[0], z0l[0]); split8(wh_z + 8, z0h[1], z0l[1]);
        s8v owh[2], owl[2];
        {
            float ov[16];
            #pragma unroll
            for (int c = 0; c < 2; ++c)
                #pragma unroll
                for (int jj = 0; jj < 8; ++jj)
                    ov[c * 8 + jj] = outW_l[col][c * 32 + q * 8 + jj];
            split8(ov, owh[0], owl[0]); split8(ov + 8, owh[1], owl[1]);
        }

        float b_r = dbhh[u] + dbih[u];
        float b_z = dbhh[u + 64] + dbih[u + 64];
        float b_in = dbih[u + 128];
        const float b_hn = dbhh[u + 128];
        #pragma unroll
        for (int j = 0; j < 16; ++j) {
            float obj = outb[j];
            b_r  = fmaf(obj, wi_r[j], b_r);
            b_z  = fmaf(obj, wi_z[j], b_z);
            b_in = fmaf(obj, wi_n[j], b_in);
        }
        const float ob = outb[col];

        float g_r[2], g_z[2], g_n[2];
        #pragma unroll
        for (int j2 = 0; j2 < 2; ++j2) {
            int row = rj0 + j2;
            float sr = dbih[u] + dbhh[u];
            float sz = dbih[u + 64] + dbhh[u + 64];
            float sn = dbih[u + 128];
            #pragma unroll
            for (int j = 0; j < 16; ++j) {
                float iv = init_l[row][j];
                sr = fmaf(wi_r[j], iv, sr);
                sz = fmaf(wi_z[j], iv, sz);
                sn = fmaf(wi_n[j], iv, sn);
            }
            g_r[j2] = sr; g_z[j2] = sz; g_n[j2] = sn;
        }

        // ---- dec step 0: h1 = GRU(h0, init_in); h0 already in buf0 ----
        {
            const s8v ah0 = *(const s8v*)&hiL[0][col][q * 8];
            const s8v al0 = *(const s8v*)&loL[0][col][q * 8];
            const s8v ah1 = *(const s8v*)&hiL[0][col][32 + q * 8];
            const s8v al1 = *(const s8v*)&loL[0][col][32 + q * 8];
            f4v ar, az, ahn;
            ar  = MFMA16(ah0, r0h[0], z4);
            az  = MFMA16(ah0, z0h[0], z4);
            ahn = MFMA16(ah0, hnh[0], z4);
            ar  = MFMA16(ah0, r0l[0], ar);
            az  = MFMA16(ah0, z0l[0], az);
            ahn = MFMA16(ah0, hnl[0], ahn);
            ar  = MFMA16(al0, r0h[0], ar);
            az  = MFMA16(al0, z0h[0], az);
            ahn = MFMA16(al0, hnh[0], ahn);
            ar  = MFMA16(ah1, r0h[1], ar);
            az  = MFMA16(ah1, z0h[1], az);
            ahn = MFMA16(ah1, hnh[1], ahn);
            ar  = MFMA16(ah1, r0l[1], ar);
            az  = MFMA16(ah1, z0l[1], az);
            ahn = MFMA16(ah1, hnl[1], ahn);
            ar  = MFMA16(al1, r0h[1], ar);
            az  = MFMA16(al1, z0h[1], az);
            ahn = MFMA16(al1, hnh[1], ahn);

            float pr[2], pz[2], pnh[2];
            pr[0]  = half_merge(ar[0],  ar[2]);
            pr[1]  = half_merge(ar[1],  ar[3]);
            pz[0]  = half_merge(az[0],  az[2]);
            pz[1]  = half_merge(az[1],  az[3]);
            pnh[0] = half_merge(ahn[0], ahn[2]);
            pnh[1] = half_merge(ahn[1], ahn[3]);

            #pragma unroll
            for (int j = 0; j < 2; ++j) {
                float r  = sigmoidf_(pr[j] + g_r[j]);
                float zz = sigmoidf_(pz[j] + g_z[j]);
                float n  = tanhf_(g_n[j] + r * (pnh[j] + b_hn));
                float h  = (1.0f - zz) * n + zz * hold2[j];
                hold2[j] = h;
                unsigned short hh = f2bf(h);
                hiL[1][rj0 + j][u] = hh;
                loL[1][rj0 + j][u] = f2bf(h - bf2f(hh));
            }
            __syncthreads();
        }

        // ---- dec steps 1..99; o_{t-1} by wave (t-1)&3 ----
        for (int t = 1; t < SEQLEN; ++t) {
            const int dcur = t & 1;
            const s8v ah0 = *(const s8v*)&hiL[dcur][col][q * 8];
            const s8v al0 = *(const s8v*)&loL[dcur][col][q * 8];
            const s8v ah1 = *(const s8v*)&hiL[dcur][col][32 + q * 8];
            const s8v al1 = *(const s8v*)&loL[dcur][col][32 + q * 8];

            if (w == ((t - 1) & 3)) {
                f4v oa;
                oa = MFMA16(ah0, owh[0], z4);
                oa = MFMA16(ah0, owl[0], oa);
                oa = MFMA16(al0, owh[0], oa);
                oa = MFMA16(ah1, owh[1], oa);
                oa = MFMA16(ah1, owl[1], oa);
                oa = MFMA16(al1, owh[1], oa);
                if (q < 2) {
                    #pragma unroll
                    for (int i = 0; i < 4; ++i)
                        dec_o[(((size_t)(b0 + q * 4 + i) * SEQLEN) + (t - 1)) * INDIM + col] = oa[i] + ob;
                }
            }

            f4v ar, az, ain, ahn;
            ar  = MFMA16(ah0, mrh[0], z4);
            az  = MFMA16(ah0, mzh[0], z4);
            ain = MFMA16(ah0, cinh[0], z4);
            ahn = MFMA16(ah0, hnh[0], z4);
            ar  = MFMA16(ah0, mrl[0], ar);
            az  = MFMA16(ah0, mzl[0], az);
            ain = MFMA16(ah0, cinl[0], ain);
            ahn = MFMA16(ah0, hnl[0], ahn);
            ar  = MFMA16(al0, mrh[0], ar);
            az  = MFMA16(al0, mzh[0], az);
            ain = MFMA16(al0, cinh[0], ain);
            ahn = MFMA16(al0, hnh[0], ahn);
            ar  = MFMA16(ah1, mrh[1], ar);
            az  = MFMA16(ah1, mzh[1], az);
            ain = MFMA16(ah1, cinh[1], ain);
            ahn = MFMA16(ah1, hnh[1], ahn);
            ar  = MFMA16(ah1, mrl[1], ar);
            az  = MFMA16(ah1, mzl[1], az);
            ain = MFMA16(ah1, cinl[1], ain);
            ahn = MFMA16(ah1, hnl[1], ahn);
            ar  = MFMA16(al1, mrh[1], ar);
            az  = MFMA16(al1, mzh[1], az);
            ain = MFMA16(al1, cinh[1], ain);
            ahn = MFMA16(al1, hnh[1], ahn);

            float pr[2], pz[2], pin[2], pnh[2];
            pr[0]  = half_merge(ar[0],  ar[2]);
            pr[1]  = half_merge(ar[1],  ar[3]);
            pz[0]  = half_merge(az[0],  az[2]);
            pz[1]  = half_merge(az[1],  az[3]);
            pin[0] = half_merge(ain[0], ain[2]);
            pin[1] = half_merge(ain[1], ain[3]);
            pnh[0] = half_merge(ahn[0], ahn[2]);
            pnh[1] = half_merge(ahn[1], ahn[3]);

            const int nxt = dcur ^ 1;
            #pragma unroll
            for (int j = 0; j < 2; ++j) {
                float r  = sigmoidf_(pr[j] + b_r);
                float zz = sigmoidf_(pz[j] + b_z);
                float n  = tanhf_(pin[j] + b_in + r * (pnh[j] + b_hn));
                float h  = (1.0f - zz) * n + zz * hold2[j];
                hold2[j] = h;
                unsigned short hh = f2bf(h);
                hiL[nxt][rj0 + j][u] = hh;
                loL[nxt][rj0 + j][u] = f2bf(h - bf2f(hh));
            }
            __syncthreads();
        }

        // ---- epilogue: o_99 = h_100 @ outW^T + outb (buf 0) ----
        if (w == 0) {
            const s8v ah0 = *(const s8v*)&hiL[0][col][q * 8];
            const s8v al0 = *(const s8v*)&loL[0][col][q * 8];
            const s8v ah1 = *(const s8v*)&hiL[0][col][32 + q * 8];
            const s8v al1 = *(const s8v*)&loL[0][col][32 + q * 8];
            f4v oa;
            oa = MFMA16(ah0, owh[0], z4);
            oa = MFMA16(ah0, owl[0], oa);
            oa = MFMA16(al0, owh[0], oa);
            oa = MFMA16(ah1, owh[1], oa);
            oa = MFMA16(ah1, owl[1], oa);
            oa = MFMA16(al1, owh[1], oa);
            if (q < 2) {
                #pragma unroll
                for (int i = 0; i < 4; ++i)
                    dec_o[(((size_t)(b0 + q * 4 + i) * SEQLEN) + (SEQLEN - 1)) * INDIM + col] = oa[i] + ob;
            }
        }
    }
}

// =====================================================================
// Heads: 409600 rows. R6: 2 rows/thread (halves the proven LDS-pipe
// bottleneck: 12 broadcast ds_read_b128/iter now feed 140 FMAs).
// Moderate VGPR (~130) unlike the failed 4-row variant. Math identical.
// =====================================================================
__global__ __launch_bounds__(256) void heads_kernel(
    const float* __restrict__ dec_o,
    const float* __restrict__ mW1, const float* __restrict__ mb1,
    const float* __restrict__ mW2, const float* __restrict__ mb2,
    const float* __restrict__ cW1, const float* __restrict__ cb1,
    const float* __restrict__ cW2, const float* __restrict__ cb2,
    float* __restrict__ out)
{
    const int tid = threadIdx.x;

    __shared__ __align__(16) float lW1m[64][16];
    __shared__ __align__(16) float lW1c[64][16];
    // [hu][0..3]=mW2 rows, [4..13]=cW2 rows, [14]=mb1, [15]=cb1
    __shared__ __align__(16) float lW2t[64][16];

    for (int i = tid; i < 1024; i += 256) {
        lW1m[i >> 4][i & 15] = mW1[i];
        lW1c[i >> 4][i & 15] = cW1[i];
    }
    if (tid < 64) {
        #pragma unroll
        for (int j = 0; j < 4; ++j)  lW2t[tid][j]     = mW2[j * 64 + tid];
        #pragma unroll
        for (int j = 0; j < 10; ++j) lW2t[tid][4 + j] = cW2[j * 64 + tid];
        lW2t[tid][14] = mb1[tid];
        lW2t[tid][15] = cb1[tid];
    }
    __syncthreads();

    const size_t r0 = (size_t)blockIdx.x * 512 + tid;  // rows r0, r0+256

    float o[2][16];
    #pragma unroll
    for (int k = 0; k < 2; ++k) {
        const float4* op = (const float4*)(dec_o + (r0 + (size_t)k * 256) * 16);
        #pragma unroll
        for (int c = 0; c < 4; ++c) {
            float4 v = op[c];
            o[k][4 * c + 0] = v.x; o[k][4 * c + 1] = v.y;
            o[k][4 * c + 2] = v.z; o[k][4 * c + 3] = v.w;
        }
    }

    float m[2][4], cv[2][10];
    #pragma unroll
    for (int k = 0; k < 2; ++k) {
        #pragma unroll
        for (int j = 0; j < 4; ++j)  m[k][j]  = mb2[j];
        #pragma unroll
        for (int j = 0; j < 10; ++j) cv[k][j] = cb2[j];
    }

    #pragma unroll 2
    for (int hu = 0; hu < 64; ++hu) {
        const float4 a0 = *(const float4*)&lW1m[hu][0];
        const float4 a1 = *(const float4*)&lW1m[hu][4];
        const float4 a2 = *(const float4*)&lW1m[hu][8];
        const float4 a3 = *(const float4*)&lW1m[hu][12];
        const float4 c0 = *(const float4*)&lW1c[hu][0];
        const float4 c1 = *(const float4*)&lW1c[hu][4];
        const float4 c2 = *(const float4*)&lW1c[hu][8];
        const float4 c3 = *(const float4*)&lW1c[hu][12];
        const float4 t0 = *(const float4*)&lW2t[hu][0];
        const float4 t1 = *(const float4*)&lW2t[hu][4];
        const float4 t2 = *(const float4*)&lW2t[hu][8];
        const float4 t3 = *(const float4*)&lW2t[hu][12];

        #pragma unroll
        for (int k = 0; k < 2; ++k) {
            float hm = t3.z;  // mb1[hu]
            hm = fmaf(a0.x, o[k][0],  hm); hm = fmaf(a0.y, o[k][1],  hm);
            hm = fmaf(a0.z, o[k][2],  hm); hm = fmaf(a0.w, o[k][3],  hm);
            hm = fmaf(a1.x, o[k][4],  hm); hm = fmaf(a1.y, o[k][5],  hm);
            hm = fmaf(a1.z, o[k][6],  hm); hm = fmaf(a1.w, o[k][7],  hm);
            hm = fmaf(a2.x, o[k][8],  hm); hm = fmaf(a2.y, o[k][9],  hm);
            hm = fmaf(a2.z, o[k][10], hm); hm = fmaf(a2.w, o[k][11], hm);
            hm = fmaf(a3.x, o[k][12], hm); hm = fmaf(a3.y, o[k][13], hm);
            hm = fmaf(a3.z, o[k][14], hm); hm = fmaf(a3.w, o[k][15], hm);
            float gm = gelu_fast(hm);
            m[k][0] = fmaf(t0.x, gm, m[k][0]); m[k][1] = fmaf(t0.y, gm, m[k][1]);
            m[k][2] = fmaf(t0.z, gm, m[k][2]); m[k][3] = fmaf(t0.w, gm, m[k][3]);

            float hc = t3.w;  // cb1[hu]
            hc = fmaf(c0.x, o[k][0],  hc); hc = fmaf(c0.y, o[k][1],  hc);
            hc = fmaf(c0.z, o[k][2],  hc); hc = fmaf(c0.w, o[k][3],  hc);
            hc = fmaf(c1.x, o[k][4],  hc); hc = fmaf(c1.y, o[k][5],  hc);
            hc = fmaf(c1.z, o[k][6],  hc); hc = fmaf(c1.w, o[k][7],  hc);
            hc = fmaf(c2.x, o[k][8],  hc); hc = fmaf(c2.y, o[k][9],  hc);
            hc = fmaf(c2.z, o[k][10], hc); hc = fmaf(c2.w, o[k][11], hc);
            hc = fmaf(c3.x, o[k][12], hc); hc = fmaf(c3.y, o[k][13], hc);
            hc = fmaf(c3.z, o[k][14], hc); hc = fmaf(c3.w, o[k][15], hc);
            float gc = gelu_fast(hc);
            cv[k][0] = fmaf(t1.x, gc, cv[k][0]); cv[k][1] = fmaf(t1.y, gc, cv[k][1]);
            cv[k][2] = fmaf(t1.z, gc, cv[k][2]); cv[k][3] = fmaf(t1.w, gc, cv[k][3]);
            cv[k][4] = fmaf(t2.x, gc, cv[k][4]); cv[k][5] = fmaf(t2.y, gc, cv[k][5]);
            cv[k][6] = fmaf(t2.z, gc, cv[k][6]); cv[k][7] = fmaf(t2.w, gc, cv[k][7]);
            cv[k][8] = fmaf(t3.x, gc, cv[k][8]); cv[k][9] = fmaf(t3.y, gc, cv[k][9]);
        }
    }

    float* means = out;
    float* covs  = out + MEANS_N;
    #pragma unroll
    for (int k = 0; k < 2; ++k) {
        const size_t r = r0 + (size_t)k * 256;
        m[k][2] = fminf(fmaxf(m[k][2], -1.0f), 1.0f);
        m[k][3] = fminf(fmaxf(m[k][3], -1.0f), 1.0f);
        #pragma unroll
        for (int j = 0; j < 4; ++j)  means[r * 4 + j] = m[k][j];
        #pragma unroll
        for (int j = 0; j < 10; ++j) covs[r * 10 + j] = cv[k][j];
    }
}

// =====================================================================
extern "C" void kernel_launch(void* const* d_in, const int* in_sizes, int n_in,
                              void* d_out, int out_size, void* d_ws, size_t ws_size,
                              hipStream_t stream)
{
    const float* x    = (const float*)d_in[0];
    const float* trg  = (const float*)d_in[1];
    const float* eWih = (const float*)d_in[2];
    const float* ebih = (const float*)d_in[3];
    const float* eWhh = (const float*)d_in[4];
    const float* ebhh = (const float*)d_in[5];
    const float* dWih = (const float*)d_in[6];
    const float* dbih = (const float*)d_in[7];
    const float* dWhh = (const float*)d_in[8];
    const float* dbhh = (const float*)d_in[9];
    const float* outW = (const float*)d_in[10];
    const float* outb = (const float*)d_in[11];
    const float* embW = (const float*)d_in[12];
    const float* embb = (const float*)d_in[13];
    const float* mW1  = (const float*)d_in[14];
    const float* mb1  = (const float*)d_in[15];
    const float* mW2  = (const float*)d_in[16];
    const float* mb2  = (const float*)d_in[17];
    const float* cW1  = (const float*)d_in[18];
    const float* cb1  = (const float*)d_in[19];
    const float* cW2  = (const float*)d_in[20];
    const float* cb2  = (const float*)d_in[21];

    float* ws    = (float*)d_ws;
    float* dec_o = ws;                          // 4096*100*16 = 6553600 floats
    float* outp  = (float*)d_out;

    fused_gru_kernel<<<dim3(BTOT / 8), dim3(256), 0, stream>>>(
        x, eWih, ebih, eWhh, ebhh, dWih, dbih, dWhh, dbhh,
        outW, outb, embW, embb, trg, dec_o);
    heads_kernel<<<dim3((BTOT * SEQLEN) / 512), dim3(256), 0, stream>>>(
        dec_o, mW1, mb1, mW2, mb2, cW1, cb1, cW2, cb2, outp);
}

// Round 6
// 348.986 us; speedup vs baseline: 1.0738x; 1.0271x over previous
//
#include <hip/hip_runtime.h>
#include <cstdint>
#include <cstddef>

// Problem constants (match reference)
#define BTOT    4096
#define SRCLEN  128
#define INDIM   16
#define HDIM    64
#define SEQLEN  100
#define MEANS_N (BTOT * SEQLEN * 4)   // 1638400

// ---------- helpers ----------
__device__ __forceinline__ float sigmoidf_(float x) {
    return __builtin_amdgcn_rcpf(1.0f + __expf(-x));
}
__device__ __forceinline__ float tanhf_(float x) {
    float e = __expf(2.0f * x);
    return 1.0f - 2.0f * __builtin_amdgcn_rcpf(e + 1.0f);
}
// gelu via Abramowitz-Stegun 7.1.26 erf (|err| < 1.5e-7)
__device__ __forceinline__ float gelu_fast(float x) {
    float z = fabsf(x) * 0.70710678118654752440f;
    float t = __builtin_amdgcn_rcpf(1.0f + 0.3275911f * z);
    float p = t * (0.254829592f +
              t * (-0.284496736f +
              t * (1.421413741f +
              t * (-1.453152027f +
              t * 1.061405429f))));
    float er = 1.0f - p * __expf(-z * z);
    er = copysignf(er, x);
    return 0.5f * x * (1.0f + er);
}

// ---------- bf16 split helpers (bf16x3 emulated-fp32 MFMA) ----------
typedef __attribute__((ext_vector_type(8))) short s8v;   // 8 bf16 (4 VGPRs)
typedef __attribute__((ext_vector_type(4))) float f4v;   // 4 fp32

__device__ __forceinline__ unsigned short f2bf(float x) {  // RTNE float -> bf16 bits
    unsigned u = __float_as_uint(x);
    unsigned r = (u + 0x7FFFu + ((u >> 16) & 1u)) >> 16;
    return (unsigned short)r;
}
__device__ __forceinline__ float bf2f(unsigned short b) {
    return __uint_as_float(((unsigned)b) << 16);
}
__device__ __forceinline__ void split2(float4 a, float4 b, s8v& hi, s8v& lo) {
    float v[8] = {a.x, a.y, a.z, a.w, b.x, b.y, b.z, b.w};
    #pragma unroll
    for (int j = 0; j < 8; ++j) {
        unsigned short h = f2bf(v[j]);
        hi[j] = (short)h;
        lo[j] = (short)f2bf(v[j] - bf2f(h));
    }
}
__device__ __forceinline__ void split8(const float* v, s8v& hi, s8v& lo) {
    #pragma unroll
    for (int j = 0; j < 8; ++j) {
        unsigned short h = f2bf(v[j]);
        hi[j] = (short)h;
        lo[j] = (short)f2bf(v[j] - bf2f(h));
    }
}
__device__ __forceinline__ void load_bfrag(const float* p, s8v& hi, s8v& lo) {
    float4 a = *(const float4*)p;
    float4 b = *(const float4*)(p + 4);
    split2(a, b, hi, lo);
}

// permlane32_swap merge: lanes 0-31 keep own_lo, lanes 32-63 get send_hi
// from lane-32. Single VALU op.
typedef __attribute__((ext_vector_type(2))) unsigned int u2v;
__device__ __forceinline__ float half_merge(float own_lo, float send_hi) {
    u2v r = __builtin_amdgcn_permlane32_swap(__float_as_uint(own_lo),
                                             __float_as_uint(send_hi),
                                             false, false);
    return __uint_as_float(r[0]);
}

#define MFMA16(a, b, c) __builtin_amdgcn_mfma_f32_16x16x32_bf16((a), (b), (c), 0, 0, 0)

// =====================================================================
// FUSED encoder + decoder GRU — byte-identical to R5 (measured 212 µs).
// =====================================================================
__global__ __launch_bounds__(256, 2) void fused_gru_kernel(
    const float* __restrict__ x,
    const float* __restrict__ eWih, const float* __restrict__ ebih,
    const float* __restrict__ eWhh, const float* __restrict__ ebhh,
    const float* __restrict__ dWih, const float* __restrict__ dbih,
    const float* __restrict__ dWhh, const float* __restrict__ dbhh,
    const float* __restrict__ outW, const float* __restrict__ outb,
    const float* __restrict__ embW, const float* __restrict__ embb,
    const float* __restrict__ trg,
    float* __restrict__ dec_o)
{
    const int tid  = threadIdx.x;
    const int lane = tid & 63;
    const int w    = tid >> 6;     // wave 0..3
    const int col  = lane & 15;
    const int q    = lane >> 4;
    const int u    = w * 16 + col;
    const int b0   = blockIdx.x * 8;
    // post-rebalance batch row for item j: rows {0,1},{4,5},{2,3},{6,7} for q=0..3
    const int rj0  = (q & 1) * 4 + ((q >> 1) << 1);

    __shared__ __align__(16) unsigned short hiL[2][16][72];
    __shared__ __align__(16) unsigned short loL[2][16][72];
    // enc x tile: [tl][batch 0..7 | zero-row 8][dim]
    __shared__ __align__(16) unsigned short xhi_l[64][9][16];
    __shared__ __align__(16) unsigned short xlo_l[64][9][16];
    // dec helpers (staged up front; read only after the first barrier)
    __shared__ float outW_l[16][64];
    __shared__ float init_l[8][16];

    // ---- stage dec LDS (outW, init_in) ----
    for (int i = tid; i < 16 * 64; i += 256) outW_l[i >> 6][i & 63] = outW[i];
    if (tid < 128) {
        int b = tid >> 4, jj = tid & 15;
        float s = embb[jj];
        #pragma unroll
        for (int s4 = 0; s4 < 4; ++s4)
            s = fmaf(embW[jj * 4 + s4], trg[(size_t)(b0 + b) * 4 + s4], s);
        init_l[b][jj] = s;
    }

    // ---- enc init: zero both h buffers (rows 8-15 stay zero forever) ----
    for (int i = tid; i < 2 * 16 * 72; i += 256) {
        ((unsigned short*)hiL)[i] = 0;
        ((unsigned short*)loL)[i] = 0;
    }
    for (int i = tid; i < 64 * 16; i += 256) {
        xhi_l[i >> 4][8][i & 15] = 0;
        xlo_l[i >> 4][8][i & 15] = 0;
    }

    // stage one 64-step chunk of x, pre-split into bf16 hi/lo
    auto stage_x = [&](int c) {
        #pragma unroll
        for (int k = 0; k < 8; ++k) {
            int f   = tid + k * 256;
            int b   = f >> 8;
            int rem = f & 255;
            int tl  = rem >> 2;
            int d4  = (rem & 3) << 2;
            const float* xp = x + ((size_t)(b0 + b) * SRCLEN + (c * 64 + tl)) * INDIM + d4;
            float4 v = *(const float4*)xp;
            float vv[4] = {v.x, v.y, v.z, v.w};
            unsigned short hh[4], ll[4];
            #pragma unroll
            for (int j = 0; j < 4; ++j) {
                hh[j] = f2bf(vv[j]);
                ll[j] = f2bf(vv[j] - bf2f(hh[j]));
            }
            *(ushort4*)&xhi_l[tl][b][d4] = make_ushort4(hh[0], hh[1], hh[2], hh[3]);
            *(ushort4*)&xlo_l[tl][b][d4] = make_ushort4(ll[0], ll[1], ll[2], ll[3]);
        }
    };

    const s8v z8 = {0, 0, 0, 0, 0, 0, 0, 0};
    const f4v z4 = {0.0f, 0.0f, 0.0f, 0.0f};

    // ================= ENCODER PHASE =================
    {
        s8v brh[3], brl[3], bzh[3], bzl[3], bnhh[2], bnhl[2], bnxh, bnxl;
        load_bfrag(eWhh + (size_t)u * 64 + q * 8,              brh[0], brl[0]);
        load_bfrag(eWhh + (size_t)u * 64 + 32 + q * 8,         brh[1], brl[1]);
        load_bfrag(eWhh + (size_t)(64 + u) * 64 + q * 8,       bzh[0], bzl[0]);
        load_bfrag(eWhh + (size_t)(64 + u) * 64 + 32 + q * 8,  bzh[1], bzl[1]);
        load_bfrag(eWhh + (size_t)(128 + u) * 64 + q * 8,      bnhh[0], bnhl[0]);
        load_bfrag(eWhh + (size_t)(128 + u) * 64 + 32 + q * 8, bnhh[1], bnhl[1]);
        if (q < 2) {
            load_bfrag(eWih + (size_t)u * 16 + q * 8,         brh[2], brl[2]);
            load_bfrag(eWih + (size_t)(64 + u) * 16 + q * 8,  bzh[2], bzl[2]);
            load_bfrag(eWih + (size_t)(128 + u) * 16 + q * 8, bnxh, bnxl);
        } else {
            brh[2] = z8; brl[2] = z8; bzh[2] = z8; bzl[2] = z8; bnxh = z8; bnxl = z8;
        }

        const float br   = ebih[u] + ebhh[u];
        const float bz   = ebih[u + 64] + ebhh[u + 64];
        const float bnx  = ebih[u + 128];
        const float bnh  = ebhh[u + 128];

        const int xb   = (q < 2) ? (col & 7) : 8;
        const int xoff = (q & 1) * 8;
        const unsigned short* xh_base = &xhi_l[0][xb][xoff];
        const unsigned short* xl_base = &xlo_l[0][xb][xoff];

        stage_x(0);
        float hold2e[2] = {0.0f, 0.0f};
        __syncthreads();

        int cur = 0;
        for (int t = 0; t < SRCLEN; ++t) {
            if (t == 64) {
                stage_x(1);
                __syncthreads();
            }
            const int tl = t & 63;

            const s8v xh = *(const s8v*)(xh_base + (size_t)tl * 144);
            const s8v xl = *(const s8v*)(xl_base + (size_t)tl * 144);

            const s8v ah0 = *(const s8v*)&hiL[cur][col][q * 8];
            const s8v al0 = *(const s8v*)&loL[cur][col][q * 8];
            const s8v ah1 = *(const s8v*)&hiL[cur][col][32 + q * 8];
            const s8v al1 = *(const s8v*)&loL[cur][col][32 + q * 8];

            f4v accr, accz, accnh, accnx;
            accr  = MFMA16(ah0, brh[0], z4);
            accz  = MFMA16(ah0, bzh[0], z4);
            accnh = MFMA16(ah0, bnhh[0], z4);
            accr  = MFMA16(ah0, brl[0], accr);
            accz  = MFMA16(ah0, bzl[0], accz);
            accnh = MFMA16(ah0, bnhl[0], accnh);
            accr  = MFMA16(al0, brh[0], accr);
            accz  = MFMA16(al0, bzh[0], accz);
            accnh = MFMA16(al0, bnhh[0], accnh);
            accr  = MFMA16(ah1, brh[1], accr);
            accz  = MFMA16(ah1, bzh[1], accz);
            accnh = MFMA16(ah1, bnhh[1], accnh);
            accr  = MFMA16(ah1, brl[1], accr);
            accz  = MFMA16(ah1, bzl[1], accz);
            accnh = MFMA16(ah1, bnhl[1], accnh);
            accr  = MFMA16(al1, brh[1], accr);
            accz  = MFMA16(al1, bzh[1], accz);
            accnh = MFMA16(al1, bnhh[1], accnh);
            accr  = MFMA16(xh, brh[2], accr);
            accz  = MFMA16(xh, bzh[2], accz);
            accnx = MFMA16(xh, bnxh, z4);
            accr  = MFMA16(xh, brl[2], accr);
            accz  = MFMA16(xh, bzl[2], accz);
            accnx = MFMA16(xh, bnxl, accnx);
            accr  = MFMA16(xl, brh[2], accr);
            accz  = MFMA16(xl, bzh[2], accz);
            accnx = MFMA16(xl, bnxh, accnx);

            float pr[2], pz[2], pnh[2], pnx[2];
            pr[0]  = half_merge(accr[0],  accr[2]);
            pr[1]  = half_merge(accr[1],  accr[3]);
            pz[0]  = half_merge(accz[0],  accz[2]);
            pz[1]  = half_merge(accz[1],  accz[3]);
            pnh[0] = half_merge(accnh[0], accnh[2]);
            pnh[1] = half_merge(accnh[1], accnh[3]);
            pnx[0] = half_merge(accnx[0], accnx[2]);
            pnx[1] = half_merge(accnx[1], accnx[3]);

            const int nxt = cur ^ 1;
            #pragma unroll
            for (int j = 0; j < 2; ++j) {
                float r  = sigmoidf_(pr[j] + br);
                float zz = sigmoidf_(pz[j] + bz);
                float n  = tanhf_(pnx[j] + bnx + r * (pnh[j] + bnh));
                float h  = (1.0f - zz) * n + zz * hold2e[j];
                hold2e[j] = h;
                unsigned short hh = f2bf(h);
                hiL[nxt][rj0 + j][u] = hh;
                loL[nxt][rj0 + j][u] = f2bf(h - bf2f(hh));
            }
            __syncthreads();
            cur ^= 1;
        }

        // ================= DECODER PHASE =================
        float hold2[2] = {hold2e[0], hold2e[1]};

        float wh_r[16], wh_z[16], wh_n[16];
        #pragma unroll
        for (int c = 0; c < 2; ++c)
            #pragma unroll
            for (int jj = 0; jj < 8; ++jj) {
                int k = c * 32 + q * 8 + jj;
                wh_r[c * 8 + jj] = dWhh[(size_t)u * 64 + k];
                wh_z[c * 8 + jj] = dWhh[(size_t)(64 + u) * 64 + k];
                wh_n[c * 8 + jj] = dWhh[(size_t)(128 + u) * 64 + k];
            }
        float wi_r[16], wi_z[16], wi_n[16];
        #pragma unroll
        for (int j = 0; j < 16; ++j) {
            wi_r[j] = dWih[(size_t)u * 16 + j];
            wi_z[j] = dWih[(size_t)(64 + u) * 16 + j];
            wi_n[j] = dWih[(size_t)(128 + u) * 16 + j];
        }

        float m_r[16], m_z[16], c_in[16];
        #pragma unroll
        for (int c = 0; c < 2; ++c)
            #pragma unroll
            for (int jj = 0; jj < 8; ++jj) {
                int k = c * 32 + q * 8 + jj;
                float sr = 0.0f, sz = 0.0f, sn = 0.0f;
                #pragma unroll
                for (int j = 0; j < 16; ++j) {
                    float ow = outW_l[j][k];
                    sr = fmaf(wi_r[j], ow, sr);
                    sz = fmaf(wi_z[j], ow, sz);
                    sn = fmaf(wi_n[j], ow, sn);
                }
                m_r[c * 8 + jj]  = wh_r[c * 8 + jj] + sr;
                m_z[c * 8 + jj]  = wh_z[c * 8 + jj] + sz;
                c_in[c * 8 + jj] = sn;
            }

        s8v mrh[2], mrl[2], mzh[2], mzl[2], cinh[2], cinl[2], hnh[2], hnl[2];
        split8(m_r,      mrh[0],  mrl[0]);  split8(m_r + 8,  mrh[1],  mrl[1]);
        split8(m_z,      mzh[0],  mzl[0]);  split8(m_z + 8,  mzh[1],  mzl[1]);
        split8(c_in,     cinh[0], cinl[0]); split8(c_in + 8, cinh[1], cinl[1]);
        split8(wh_n,     hnh[0],  hnl[0]);  split8(wh_n + 8, hnh[1],  hnl[1]);
        s8v r0h[2], r0l[2], z0h[2], z0l[2];
        split8(wh_r, r0h[0], r0l[0]); split8(wh_r + 8, r0h[1], r0l[1]);
        split8(wh_z, z0h[0], z0l[0]); split8(wh_z + 8, z0h[1], z0l[1]);
        s8v owh[2], owl[2];
        {
            float ov[16];
            #pragma unroll
            for (int c = 0; c < 2; ++c)
                #pragma unroll
                for (int jj = 0; jj < 8; ++jj)
                    ov[c * 8 + jj] = outW_l[col][c * 32 + q * 8 + jj];
            split8(ov, owh[0], owl[0]); split8(ov + 8, owh[1], owl[1]);
        }

        float b_r = dbhh[u] + dbih[u];
        float b_z = dbhh[u + 64] + dbih[u + 64];
        float b_in = dbih[u + 128];
        const float b_hn = dbhh[u + 128];
        #pragma unroll
        for (int j = 0; j < 16; ++j) {
            float obj = outb[j];
            b_r  = fmaf(obj, wi_r[j], b_r);
            b_z  = fmaf(obj, wi_z[j], b_z);
            b_in = fmaf(obj, wi_n[j], b_in);
        }
        const float ob = outb[col];

        float g_r[2], g_z[2], g_n[2];
        #pragma unroll
        for (int j2 = 0; j2 < 2; ++j2) {
            int row = rj0 + j2;
            float sr = dbih[u] + dbhh[u];
            float sz = dbih[u + 64] + dbhh[u + 64];
            float sn = dbih[u + 128];
            #pragma unroll
            for (int j = 0; j < 16; ++j) {
                float iv = init_l[row][j];
                sr = fmaf(wi_r[j], iv, sr);
                sz = fmaf(wi_z[j], iv, sz);
                sn = fmaf(wi_n[j], iv, sn);
            }
            g_r[j2] = sr; g_z[j2] = sz; g_n[j2] = sn;
        }

        // ---- dec step 0 ----
        {
            const s8v ah0 = *(const s8v*)&hiL[0][col][q * 8];
            const s8v al0 = *(const s8v*)&loL[0][col][q * 8];
            const s8v ah1 = *(const s8v*)&hiL[0][col][32 + q * 8];
            const s8v al1 = *(const s8v*)&loL[0][col][32 + q * 8];
            f4v ar, az, ahn;
            ar  = MFMA16(ah0, r0h[0], z4);
            az  = MFMA16(ah0, z0h[0], z4);
            ahn = MFMA16(ah0, hnh[0], z4);
            ar  = MFMA16(ah0, r0l[0], ar);
            az  = MFMA16(ah0, z0l[0], az);
            ahn = MFMA16(ah0, hnl[0], ahn);
            ar  = MFMA16(al0, r0h[0], ar);
            az  = MFMA16(al0, z0h[0], az);
            ahn = MFMA16(al0, hnh[0], ahn);
            ar  = MFMA16(ah1, r0h[1], ar);
            az  = MFMA16(ah1, z0h[1], az);
            ahn = MFMA16(ah1, hnh[1], ahn);
            ar  = MFMA16(ah1, r0l[1], ar);
            az  = MFMA16(ah1, z0l[1], az);
            ahn = MFMA16(ah1, hnl[1], ahn);
            ar  = MFMA16(al1, r0h[1], ar);
            az  = MFMA16(al1, z0h[1], az);
            ahn = MFMA16(al1, hnh[1], ahn);

            float pr[2], pz[2], pnh[2];
            pr[0]  = half_merge(ar[0],  ar[2]);
            pr[1]  = half_merge(ar[1],  ar[3]);
            pz[0]  = half_merge(az[0],  az[2]);
            pz[1]  = half_merge(az[1],  az[3]);
            pnh[0] = half_merge(ahn[0], ahn[2]);
            pnh[1] = half_merge(ahn[1], ahn[3]);

            #pragma unroll
            for (int j = 0; j < 2; ++j) {
                float r  = sigmoidf_(pr[j] + g_r[j]);
                float zz = sigmoidf_(pz[j] + g_z[j]);
                float n  = tanhf_(g_n[j] + r * (pnh[j] + b_hn));
                float h  = (1.0f - zz) * n + zz * hold2[j];
                hold2[j] = h;
                unsigned short hh = f2bf(h);
                hiL[1][rj0 + j][u] = hh;
                loL[1][rj0 + j][u] = f2bf(h - bf2f(hh));
            }
            __syncthreads();
        }

        // ---- dec steps 1..99 ----
        for (int t = 1; t < SEQLEN; ++t) {
            const int dcur = t & 1;
            const s8v ah0 = *(const s8v*)&hiL[dcur][col][q * 8];
            const s8v al0 = *(const s8v*)&loL[dcur][col][q * 8];
            const s8v ah1 = *(const s8v*)&hiL[dcur][col][32 + q * 8];
            const s8v al1 = *(const s8v*)&loL[dcur][col][32 + q * 8];

            if (w == ((t - 1) & 3)) {
                f4v oa;
                oa = MFMA16(ah0, owh[0], z4);
                oa = MFMA16(ah0, owl[0], oa);
                oa = MFMA16(al0, owh[0], oa);
                oa = MFMA16(ah1, owh[1], oa);
                oa = MFMA16(ah1, owl[1], oa);
                oa = MFMA16(al1, owh[1], oa);
                if (q < 2) {
                    #pragma unroll
                    for (int i = 0; i < 4; ++i)
                        dec_o[(((size_t)(b0 + q * 4 + i) * SEQLEN) + (t - 1)) * INDIM + col] = oa[i] + ob;
                }
            }

            f4v ar, az, ain, ahn;
            ar  = MFMA16(ah0, mrh[0], z4);
            az  = MFMA16(ah0, mzh[0], z4);
            ain = MFMA16(ah0, cinh[0], z4);
            ahn = MFMA16(ah0, hnh[0], z4);
            ar  = MFMA16(ah0, mrl[0], ar);
            az  = MFMA16(ah0, mzl[0], az);
            ain = MFMA16(ah0, cinl[0], ain);
            ahn = MFMA16(ah0, hnl[0], ahn);
            ar  = MFMA16(al0, mrh[0], ar);
            az  = MFMA16(al0, mzh[0], az);
            ain = MFMA16(al0, cinh[0], ain);
            ahn = MFMA16(al0, hnh[0], ahn);
            ar  = MFMA16(ah1, mrh[1], ar);
            az  = MFMA16(ah1, mzh[1], az);
            ain = MFMA16(ah1, cinh[1], ain);
            ahn = MFMA16(ah1, hnh[1], ahn);
            ar  = MFMA16(ah1, mrl[1], ar);
            az  = MFMA16(ah1, mzl[1], az);
            ain = MFMA16(ah1, cinl[1], ain);
            ahn = MFMA16(ah1, hnl[1], ahn);
            ar  = MFMA16(al1, mrh[1], ar);
            az  = MFMA16(al1, mzh[1], az);
            ain = MFMA16(al1, cinh[1], ain);
            ahn = MFMA16(al1, hnh[1], ahn);

            float pr[2], pz[2], pin[2], pnh[2];
            pr[0]  = half_merge(ar[0],  ar[2]);
            pr[1]  = half_merge(ar[1],  ar[3]);
            pz[0]  = half_merge(az[0],  az[2]);
            pz[1]  = half_merge(az[1],  az[3]);
            pin[0] = half_merge(ain[0], ain[2]);
            pin[1] = half_merge(ain[1], ain[3]);
            pnh[0] = half_merge(ahn[0], ahn[2]);
            pnh[1] = half_merge(ahn[1], ahn[3]);

            const int nxt = dcur ^ 1;
            #pragma unroll
            for (int j = 0; j < 2; ++j) {
                float r  = sigmoidf_(pr[j] + b_r);
                float zz = sigmoidf_(pz[j] + b_z);
                float n  = tanhf_(pin[j] + b_in + r * (pnh[j] + b_hn));
                float h  = (1.0f - zz) * n + zz * hold2[j];
                hold2[j] = h;
                unsigned short hh = f2bf(h);
                hiL[nxt][rj0 + j][u] = hh;
                loL[nxt][rj0 + j][u] = f2bf(h - bf2f(hh));
            }
            __syncthreads();
        }

        // ---- epilogue: o_99 ----
        if (w == 0) {
            const s8v ah0 = *(const s8v*)&hiL[0][col][q * 8];
            const s8v al0 = *(const s8v*)&loL[0][col][q * 8];
            const s8v ah1 = *(const s8v*)&hiL[0][col][32 + q * 8];
            const s8v al1 = *(const s8v*)&loL[0][col][32 + q * 8];
            f4v oa;
            oa = MFMA16(ah0, owh[0], z4);
            oa = MFMA16(ah0, owl[0], oa);
            oa = MFMA16(al0, owh[0], oa);
            oa = MFMA16(ah1, owh[1], oa);
            oa = MFMA16(ah1, owl[1], oa);
            oa = MFMA16(al1, owh[1], oa);
            if (q < 2) {
                #pragma unroll
                for (int i = 0; i < 4; ++i)
                    dec_o[(((size_t)(b0 + q * 4 + i) * SEQLEN) + (SEQLEN - 1)) * INDIM + col] = oa[i] + ob;
            }
        }
    }
}

// =====================================================================
// Heads via MFMA (R7). Per wave, per 16-row tile:
//   stage1: H = gelu(o16 @ W1^T + b1)   A: o rows (K=16, q<2 real,
//           q>=2 z8 — enc x-frag pattern); B: W1 rows (enc B pattern);
//           8 N-chunks (4 per head) x 3 bf16x3 MFMA = 24.
//   transpose: C-frag -> wave-private LDS (GRU h-write pattern, 72
//           stride), no barriers (wave-local waitcnt ordering).
//   stage2: out = H @ W2^T + b2 — exactly dec's verified o-projection
//           A/B/C mapping; 6 MFMA per head.
// 36 MFMA / 16 rows = 2.25/row vs ~82 scalar VALU/row.
// =====================================================================
__global__ __launch_bounds__(256) void heads_mfma_kernel(
    const float* __restrict__ dec_o,
    const float* __restrict__ mW1, const float* __restrict__ mb1,
    const float* __restrict__ mW2, const float* __restrict__ mb2,
    const float* __restrict__ cW1, const float* __restrict__ cb1,
    const float* __restrict__ cW2, const float* __restrict__ cb2,
    float* __restrict__ out)
{
    const int tid  = threadIdx.x;
    const int lane = tid & 63;
    const int w    = tid >> 6;
    const int col  = lane & 15;
    const int q    = lane >> 4;

    // wave-private H scratch (bf16 hi/lo, mean & cov), 72-stride anti-conflict
    __shared__ __align__(16) unsigned short Hm_hi[4][16][72];
    __shared__ __align__(16) unsigned short Hm_lo[4][16][72];
    __shared__ __align__(16) unsigned short Hc_hi[4][16][72];
    __shared__ __align__(16) unsigned short Hc_lo[4][16][72];

    const s8v z8 = {0, 0, 0, 0, 0, 0, 0, 0};
    const f4v z4 = {0.0f, 0.0f, 0.0f, 0.0f};

    // ---- persistent B-frags: stage1 W1 (K=16 -> q<2 real) ----
    s8v w1mh[4], w1ml[4], w1ch[4], w1cl[4];
    #pragma unroll
    for (int c = 0; c < 4; ++c) {
        if (q < 2) {
            load_bfrag(mW1 + (size_t)(c * 16 + col) * 16 + q * 8, w1mh[c], w1ml[c]);
            load_bfrag(cW1 + (size_t)(c * 16 + col) * 16 + q * 8, w1ch[c], w1cl[c]);
        } else {
            w1mh[c] = z8; w1ml[c] = z8; w1ch[c] = z8; w1cl[c] = z8;
        }
    }
    // ---- persistent B-frags: stage2 W2 (K=64, 2 chunks) ----
    s8v w2mh[2], w2ml[2], w2ch[2], w2cl[2];
    if (col < 4) {
        load_bfrag(mW2 + (size_t)col * 64 + q * 8,      w2mh[0], w2ml[0]);
        load_bfrag(mW2 + (size_t)col * 64 + 32 + q * 8, w2mh[1], w2ml[1]);
    } else {
        w2mh[0] = z8; w2ml[0] = z8; w2mh[1] = z8; w2ml[1] = z8;
    }
    if (col < 10) {
        load_bfrag(cW2 + (size_t)col * 64 + q * 8,      w2ch[0], w2cl[0]);
        load_bfrag(cW2 + (size_t)col * 64 + 32 + q * 8, w2ch[1], w2cl[1]);
    } else {
        w2ch[0] = z8; w2cl[0] = z8; w2ch[1] = z8; w2cl[1] = z8;
    }

    // ---- biases ----
    float b1m[4], b1c[4];
    #pragma unroll
    for (int c = 0; c < 4; ++c) {
        b1m[c] = mb1[c * 16 + col];
        b1c[c] = cb1[c * 16 + col];
    }
    const float b2m = (col < 4)  ? mb2[col] : 0.0f;
    const float b2c = (col < 10) ? cb2[col] : 0.0f;

    float* means = out;
    float* covs  = out + MEANS_N;

    const int wave_id = blockIdx.x * 4 + w;   // 0..6399

    #pragma unroll 1
    for (int it = 0; it < 4; ++it) {
        const int tile = wave_id + 6400 * it;     // 0..25599
        const size_t r0 = (size_t)tile * 16;

        // ---- A-frags: 16 rows of dec_o, K=16 (q<2 real, else zero) ----
        s8v ah, al;
        if (q < 2) {
            load_bfrag(dec_o + (r0 + (size_t)col) * 16 + q * 8, ah, al);
        } else { ah = z8; al = z8; }

        // ---- stage1: per N-chunk 3 MFMA, gelu, split, write to LDS ----
        #pragma unroll
        for (int c = 0; c < 4; ++c) {
            f4v am = MFMA16(ah, w1mh[c], z4);
            am = MFMA16(ah, w1ml[c], am);
            am = MFMA16(al, w1mh[c], am);
            f4v ac = MFMA16(ah, w1ch[c], z4);
            ac = MFMA16(ah, w1cl[c], ac);
            ac = MFMA16(al, w1ch[c], ac);
            #pragma unroll
            for (int i = 0; i < 4; ++i) {
                float hm = gelu_fast(am[i] + b1m[c]);
                unsigned short hh = f2bf(hm);
                Hm_hi[w][q * 4 + i][c * 16 + col] = hh;
                Hm_lo[w][q * 4 + i][c * 16 + col] = f2bf(hm - bf2f(hh));
                float hc = gelu_fast(ac[i] + b1c[c]);
                hh = f2bf(hc);
                Hc_hi[w][q * 4 + i][c * 16 + col] = hh;
                Hc_lo[w][q * 4 + i][c * 16 + col] = f2bf(hc - bf2f(hh));
            }
        }

        // ---- stage2 A-frags (wave-local LDS read; waitcnt-ordered) ----
        const s8v amh0 = *(const s8v*)&Hm_hi[w][col][q * 8];
        const s8v amh1 = *(const s8v*)&Hm_hi[w][col][32 + q * 8];
        const s8v aml0 = *(const s8v*)&Hm_lo[w][col][q * 8];
        const s8v aml1 = *(const s8v*)&Hm_lo[w][col][32 + q * 8];
        const s8v ach0 = *(const s8v*)&Hc_hi[w][col][q * 8];
        const s8v ach1 = *(const s8v*)&Hc_hi[w][col][32 + q * 8];
        const s8v acl0 = *(const s8v*)&Hc_lo[w][col][q * 8];
        const s8v acl1 = *(const s8v*)&Hc_lo[w][col][32 + q * 8];

        f4v om, oc;
        om = MFMA16(amh0, w2mh[0], z4);
        om = MFMA16(amh0, w2ml[0], om);
        om = MFMA16(aml0, w2mh[0], om);
        om = MFMA16(amh1, w2mh[1], om);
        om = MFMA16(amh1, w2ml[1], om);
        om = MFMA16(aml1, w2mh[1], om);
        oc = MFMA16(ach0, w2ch[0], z4);
        oc = MFMA16(ach0, w2cl[0], oc);
        oc = MFMA16(acl0, w2ch[0], oc);
        oc = MFMA16(ach1, w2ch[1], oc);
        oc = MFMA16(ach1, w2cl[1], oc);
        oc = MFMA16(acl1, w2ch[1], oc);

        // ---- store: D[row=q*4+i][n=col] (dec o-projection mapping) ----
        if (col < 4) {
            #pragma unroll
            for (int i = 0; i < 4; ++i) {
                float v = om[i] + b2m;
                if (col >= 2) v = fminf(fmaxf(v, -1.0f), 1.0f);
                means[(r0 + q * 4 + i) * 4 + col] = v;
            }
        }
        if (col < 10) {
            #pragma unroll
            for (int i = 0; i < 4; ++i)
                covs[(r0 + q * 4 + i) * 10 + col] = oc[i] + b2c;
        }
    }
}

// =====================================================================
extern "C" void kernel_launch(void* const* d_in, const int* in_sizes, int n_in,
                              void* d_out, int out_size, void* d_ws, size_t ws_size,
                              hipStream_t stream)
{
    const float* x    = (const float*)d_in[0];
    const float* trg  = (const float*)d_in[1];
    const float* eWih = (const float*)d_in[2];
    const float* ebih = (const float*)d_in[3];
    const float* eWhh = (const float*)d_in[4];
    const float* ebhh = (const float*)d_in[5];
    const float* dWih = (const float*)d_in[6];
    const float* dbih = (const float*)d_in[7];
    const float* dWhh = (const float*)d_in[8];
    const float* dbhh = (const float*)d_in[9];
    const float* outW = (const float*)d_in[10];
    const float* outb = (const float*)d_in[11];
    const float* embW = (const float*)d_in[12];
    const float* embb = (const float*)d_in[13];
    const float* mW1  = (const float*)d_in[14];
    const float* mb1  = (const float*)d_in[15];
    const float* mW2  = (const float*)d_in[16];
    const float* mb2  = (const float*)d_in[17];
    const float* cW1  = (const float*)d_in[18];
    const float* cb1  = (const float*)d_in[19];
    const float* cW2  = (const float*)d_in[20];
    const float* cb2  = (const float*)d_in[21];

    float* ws    = (float*)d_ws;
    float* dec_o = ws;                          // 4096*100*16 = 6553600 floats
    float* outp  = (float*)d_out;

    fused_gru_kernel<<<dim3(BTOT / 8), dim3(256), 0, stream>>>(
        x, eWih, ebih, eWhh, ebhh, dWih, dbih, dWhh, dbhh,
        outW, outb, embW, embb, trg, dec_o);
    heads_mfma_kernel<<<dim3(1600), dim3(256), 0, stream>>>(
        dec_o, mW1, mb1, mW2, mb2, cW1, cb1, cW2, cb2, outp);
}